// Round 1
// baseline (1614.556 us; speedup 1.0000x reference)
//
#include <hip/hip_runtime.h>
#include <math.h>

#define NSP 4096
#define CCH 512
#define EPSV 1e-5f

// ================= tiled fp32 GEMM: Y[z][m][n] = sum_k W[m][k]*X[z][k][n] + bias[m] (+R) =================
template<bool RESID>
__global__ __launch_bounds__(256) void conv_gemm(const float* __restrict__ W,
                                                 const float* __restrict__ X,
                                                 const float* __restrict__ bias,
                                                 const float* __restrict__ R,
                                                 float* __restrict__ Y)
{
    __shared__ float As[16][68];
    __shared__ float Bs[16][68];
    const int n0 = blockIdx.x * 64;
    const int m0 = blockIdx.y * 64;
    const int z  = blockIdx.z;
    const float* Xz = X + (size_t)z * CCH * NSP;
    const int t  = threadIdx.x;
    const int tx = t & 15, ty = t >> 4;
    const int ai = t >> 2, ak = (t & 3) << 2;      // A staging: row i, 4 k's
    const int bk = t >> 4, bj = (t & 15) << 2;     // B staging: k row, 4 n's
    float acc[4][4] = {};
    for (int k0 = 0; k0 < CCH; k0 += 16) {
        float4 av = *(const float4*)(W + (size_t)(m0 + ai) * CCH + k0 + ak);
        As[ak+0][ai] = av.x; As[ak+1][ai] = av.y; As[ak+2][ai] = av.z; As[ak+3][ai] = av.w;
        float4 bv = *(const float4*)(Xz + (size_t)(k0 + bk) * NSP + n0 + bj);
        *(float4*)&Bs[bk][bj] = bv;
        __syncthreads();
        #pragma unroll
        for (int kk = 0; kk < 16; ++kk) {
            float4 a = *(const float4*)&As[kk][ty << 2];
            float4 b = *(const float4*)&Bs[kk][tx << 2];
            float aa[4] = {a.x, a.y, a.z, a.w};
            float bb[4] = {b.x, b.y, b.z, b.w};
            #pragma unroll
            for (int i = 0; i < 4; ++i)
                #pragma unroll
                for (int j = 0; j < 4; ++j)
                    acc[i][j] = fmaf(aa[i], bb[j], acc[i][j]);
        }
        __syncthreads();
    }
    #pragma unroll
    for (int i = 0; i < 4; ++i) {
        const int m = m0 + (ty << 2) + i;
        const float bi = bias[m];
        float4 o = make_float4(acc[i][0] + bi, acc[i][1] + bi, acc[i][2] + bi, acc[i][3] + bi);
        const size_t off = ((size_t)z * CCH + m) * NSP + n0 + (tx << 2);
        if (RESID) {
            float4 r = *(const float4*)(R + off);
            o.x += r.x; o.y += r.y; o.z += r.z; o.w += r.w;
        }
        *(float4*)(Y + off) = o;
    }
}

// ================= QK^T: S[n][s] = sum_k Fq[k][n]*Gk[k][s]  (both [C][N] per batch) =================
__global__ __launch_bounds__(256) void qk_gemm(const float* __restrict__ Fq,
                                               const float* __restrict__ Gk,
                                               float* __restrict__ S)
{
    __shared__ float As[16][68];
    __shared__ float Bs[16][68];
    const int s0 = blockIdx.x * 64;
    const int n0 = blockIdx.y * 64;
    const int t  = threadIdx.x;
    const int tx = t & 15, ty = t >> 4;
    const int k = t >> 4, j = (t & 15) << 2;
    float acc[4][4] = {};
    for (int k0 = 0; k0 < CCH; k0 += 16) {
        *(float4*)&As[k][j] = *(const float4*)(Fq + (size_t)(k0 + k) * NSP + n0 + j);
        *(float4*)&Bs[k][j] = *(const float4*)(Gk + (size_t)(k0 + k) * NSP + s0 + j);
        __syncthreads();
        #pragma unroll
        for (int kk = 0; kk < 16; ++kk) {
            float4 a = *(const float4*)&As[kk][ty << 2];
            float4 b = *(const float4*)&Bs[kk][tx << 2];
            float aa[4] = {a.x, a.y, a.z, a.w};
            float bb[4] = {b.x, b.y, b.z, b.w};
            #pragma unroll
            for (int i = 0; i < 4; ++i)
                #pragma unroll
                for (int jj = 0; jj < 4; ++jj)
                    acc[i][jj] = fmaf(aa[i], bb[jj], acc[i][jj]);
        }
        __syncthreads();
    }
    #pragma unroll
    for (int i = 0; i < 4; ++i) {
        const int n = n0 + (ty << 2) + i;
        *(float4*)(S + (size_t)n * NSP + s0 + (tx << 2)) =
            make_float4(acc[i][0], acc[i][1], acc[i][2], acc[i][3]);
    }
}

// ================= row softmax over S (4096 per row), in place =================
__global__ __launch_bounds__(256) void row_softmax(float* __restrict__ S)
{
    const int n = blockIdx.x;
    float4* rv = (float4*)(S + (size_t)n * NSP);
    const int t = threadIdx.x;
    float4 x[4];
    float m = -3.0e38f;
    #pragma unroll
    for (int j = 0; j < 4; ++j) {
        x[j] = rv[t + j * 256];
        m = fmaxf(m, fmaxf(fmaxf(x[j].x, x[j].y), fmaxf(x[j].z, x[j].w)));
    }
    #pragma unroll
    for (int off = 32; off >= 1; off >>= 1)
        m = fmaxf(m, __shfl_xor(m, off));
    __shared__ float redm[4], reds[4];
    const int wid = t >> 6;
    if ((t & 63) == 0) redm[wid] = m;
    __syncthreads();
    m = fmaxf(fmaxf(redm[0], redm[1]), fmaxf(redm[2], redm[3]));
    float s = 0.f;
    #pragma unroll
    for (int j = 0; j < 4; ++j) {
        x[j].x = __expf(x[j].x - m); x[j].y = __expf(x[j].y - m);
        x[j].z = __expf(x[j].z - m); x[j].w = __expf(x[j].w - m);
        s += (x[j].x + x[j].y) + (x[j].z + x[j].w);
    }
    #pragma unroll
    for (int off = 32; off >= 1; off >>= 1)
        s += __shfl_xor(s, off);
    if ((t & 63) == 0) reds[wid] = s;
    __syncthreads();
    s = (reds[0] + reds[1]) + (reds[2] + reds[3]);
    const float inv = 1.0f / s;
    #pragma unroll
    for (int j = 0; j < 4; ++j) {
        x[j].x *= inv; x[j].y *= inv; x[j].z *= inv; x[j].w *= inv;
        rv[t + j * 256] = x[j];
    }
}

// ================= PV: Mean[c][n] = sum_s Hv[c][s]*P[n][s]; Sec with Hv^2 =================
__global__ __launch_bounds__(256) void pv_gemm(const float* __restrict__ Hv,
                                               const float* __restrict__ P,
                                               float* __restrict__ Mean,
                                               float* __restrict__ Sec)
{
    __shared__ float As[16][68];
    __shared__ float Bs[16][68];
    const int n0 = blockIdx.x * 64;
    const int c0 = blockIdx.y * 64;
    const int t  = threadIdx.x;
    const int tx = t & 15, ty = t >> 4;
    const int ri = t >> 2, rk = (t & 3) << 2;
    float accM[4][4] = {}, accS[4][4] = {};
    for (int k0 = 0; k0 < NSP; k0 += 16) {
        float4 av = *(const float4*)(Hv + (size_t)(c0 + ri) * NSP + k0 + rk);
        As[rk+0][ri] = av.x; As[rk+1][ri] = av.y; As[rk+2][ri] = av.z; As[rk+3][ri] = av.w;
        float4 bv = *(const float4*)(P + (size_t)(n0 + ri) * NSP + k0 + rk);
        Bs[rk+0][ri] = bv.x; Bs[rk+1][ri] = bv.y; Bs[rk+2][ri] = bv.z; Bs[rk+3][ri] = bv.w;
        __syncthreads();
        #pragma unroll
        for (int kk = 0; kk < 16; ++kk) {
            float4 a = *(const float4*)&As[kk][ty << 2];
            float4 b = *(const float4*)&Bs[kk][tx << 2];
            float aa[4] = {a.x, a.y, a.z, a.w};
            float bb[4] = {b.x, b.y, b.z, b.w};
            float a2[4] = {aa[0]*aa[0], aa[1]*aa[1], aa[2]*aa[2], aa[3]*aa[3]};
            #pragma unroll
            for (int i = 0; i < 4; ++i)
                #pragma unroll
                for (int j = 0; j < 4; ++j) {
                    accM[i][j] = fmaf(aa[i], bb[j], accM[i][j]);
                    accS[i][j] = fmaf(a2[i], bb[j], accS[i][j]);
                }
        }
        __syncthreads();
    }
    #pragma unroll
    for (int i = 0; i < 4; ++i) {
        const int c = c0 + (ty << 2) + i;
        const size_t off = (size_t)c * NSP + n0 + (tx << 2);
        *(float4*)(Mean + off) = make_float4(accM[i][0], accM[i][1], accM[i][2], accM[i][3]);
        *(float4*)(Sec  + off) = make_float4(accS[i][0], accS[i][1], accS[i][2], accS[i][3]);
    }
}

// ================= per-(b,c) content stats: mean + 1/sqrt(var_unbiased + eps) =================
__global__ __launch_bounds__(256) void content_stats(const float* __restrict__ content,
                                                     float* __restrict__ cmean,
                                                     float* __restrict__ cinv)
{
    const int bc = blockIdx.x;
    const float4* p = (const float4*)(content + (size_t)bc * NSP);
    const int t = threadIdx.x;
    float s = 0.f, s2 = 0.f;
    #pragma unroll
    for (int j = 0; j < 4; ++j) {
        float4 v = p[t + j * 256];
        s  += (v.x + v.y) + (v.z + v.w);
        s2 += (v.x*v.x + v.y*v.y) + (v.z*v.z + v.w*v.w);
    }
    #pragma unroll
    for (int off = 32; off >= 1; off >>= 1) {
        s  += __shfl_xor(s, off);
        s2 += __shfl_xor(s2, off);
    }
    __shared__ float r1[4], r2[4];
    const int wid = t >> 6;
    if ((t & 63) == 0) { r1[wid] = s; r2[wid] = s2; }
    __syncthreads();
    if (t == 0) {
        s  = (r1[0] + r1[1]) + (r1[2] + r1[3]);
        s2 = (r2[0] + r2[1]) + (r2[2] + r2[3]);
        const float mean = s * (1.0f / 4096.f);
        const float var = (s2 - 4096.f * mean * mean) * (1.0f / 4095.f);
        cmean[bc] = mean;
        cinv[bc] = rsqrtf(fmaxf(var, 0.f) + EPSV);
    }
}

// ================= O = sqrt(max(E[x^2]-E[x]^2,0)) * norm(content) + E[x] =================
__global__ __launch_bounds__(256) void compute_O(const float* __restrict__ Mean,
                                                 const float* __restrict__ Sec,
                                                 const float* __restrict__ content,
                                                 const float* __restrict__ cmean,
                                                 const float* __restrict__ cinv,
                                                 float* __restrict__ O)
{
    const int idx = blockIdx.x * 256 + threadIdx.x;   // float4 index
    const int bc = idx >> 10;                          // 1024 float4 per (b,c)
    float4 mn = ((const float4*)Mean)[idx];
    float4 sc = ((const float4*)Sec)[idx];
    float4 ct = ((const float4*)content)[idx];
    const float cm = cmean[bc], ci = cinv[bc];
    float4 o;
    o.x = sqrtf(fmaxf(sc.x - mn.x*mn.x, 0.f)) * ((ct.x - cm) * ci) + mn.x;
    o.y = sqrtf(fmaxf(sc.y - mn.y*mn.y, 0.f)) * ((ct.y - cm) * ci) + mn.y;
    o.z = sqrtf(fmaxf(sc.z - mn.z*mn.z, 0.f)) * ((ct.z - cm) * ci) + mn.z;
    o.w = sqrtf(fmaxf(sc.w - mn.w*mn.w, 0.f)) * ((ct.w - cm) * ci) + mn.w;
    ((float4*)O)[idx] = o;
}

extern "C" void kernel_launch(void* const* d_in, const int* in_sizes, int n_in,
                              void* d_out, int out_size, void* d_ws, size_t ws_size,
                              hipStream_t stream)
{
    const float* content = (const float*)d_in[0];
    const float* style   = (const float*)d_in[1];
    const float* f_w   = (const float*)d_in[2];
    const float* f_b   = (const float*)d_in[3];
    const float* g_w   = (const float*)d_in[4];
    const float* g_b   = (const float*)d_in[5];
    const float* h_w   = (const float*)d_in[6];
    const float* h_b   = (const float*)d_in[7];
    const float* out_w = (const float*)d_in[8];
    const float* out_b = (const float*)d_in[9];
    float* out = (float*)d_out;

    float* ws = (float*)d_ws;
    const size_t CN = (size_t)2 * CCH * NSP;     // 4,194,304 floats
    float* Fq    = ws;
    float* Gk    = Fq + CN;
    float* Hv    = Gk + CN;
    float* Mean  = Hv + CN;
    float* Sec   = Mean + CN;
    float* S     = Sec + CN;                     // NSP*NSP = 16,777,216 floats (reused per batch)
    float* cmean = S + (size_t)NSP * NSP;
    float* cinv  = cmean + 1024;
    float* O     = Fq;                           // safe reuse: Fq dead after last qk_gemm

    dim3 gconv(NSP / 64, CCH / 64, 2);
    conv_gemm<false><<<gconv, 256, 0, stream>>>(f_w, content, f_b, nullptr, Fq);
    conv_gemm<false><<<gconv, 256, 0, stream>>>(g_w, style,   g_b, nullptr, Gk);
    conv_gemm<false><<<gconv, 256, 0, stream>>>(h_w, style,   h_b, nullptr, Hv);
    content_stats<<<1024, 256, 0, stream>>>(content, cmean, cinv);

    for (int b = 0; b < 2; ++b) {
        const size_t boff = (size_t)b * CCH * NSP;
        qk_gemm<<<dim3(NSP / 64, NSP / 64), 256, 0, stream>>>(Fq + boff, Gk + boff, S);
        row_softmax<<<NSP, 256, 0, stream>>>(S);
        pv_gemm<<<dim3(NSP / 64, CCH / 64), 256, 0, stream>>>(Hv + boff, S, Mean + boff, Sec + boff);
    }

    compute_O<<<4096, 256, 0, stream>>>(Mean, Sec, content, cmean, cinv, O);
    conv_gemm<true><<<gconv, 256, 0, stream>>>(out_w, O, out_b, content, out);
}

// Round 3
// 621.844 us; speedup vs baseline: 2.5964x; 2.5964x over previous
//
#include <hip/hip_runtime.h>
#include <math.h>

#define NS 4096
#define CH 512
#define EPSV 1e-5f

typedef __attribute__((ext_vector_type(8))) short short8v;   // 8 x bf16 MFMA operand
typedef __attribute__((ext_vector_type(4))) float f32x4;     // MFMA accumulator
typedef unsigned short u16;

// ---------- bf16 helpers (RNE) ----------
__device__ __forceinline__ u16 f2bf(float x) {
    unsigned u = __float_as_uint(x);
    u += 0x7fff + ((u >> 16) & 1);
    return (u16)(u >> 16);
}
__device__ __forceinline__ float bf2f(u16 b) { return __uint_as_float(((unsigned)b) << 16); }

// ---------- async global->LDS, 16B per lane ----------
__device__ __forceinline__ void gload16(const void* g, void* l) {
    __builtin_amdgcn_global_load_lds((const __attribute__((address_space(1))) unsigned*)g,
                                     (__attribute__((address_space(3))) unsigned*)l, 16, 0, 0);
}

// =====================================================================================
// Generic split-bf16 GEMM:  out[m][n] = sum_k (Ahi+Alo)[k][m] * (Bhi+Blo)[k][n]  (+bias[m]) (+resid)
// A,B packed layout: element (k, x) at ((k>>3)*W + x)*8 + (k&7)   (W = Mw for A, Nw for B)
// Tile 128x128, BK=32, 4 waves (2x2), per-wave 64x64 via 4x4 frags of 16x16x32.
// 3 MFMA terms per fragment pair: hh + hl + lh  (lo*lo negligible).
// =====================================================================================
template<bool BIAS, bool RESID>
__global__ __launch_bounds__(256, 2) void gemm_split(
    const u16* __restrict__ Ahi, const u16* __restrict__ Alo,
    const u16* __restrict__ Bhi, const u16* __restrict__ Blo,
    const float* __restrict__ bias, const float* __restrict__ resid,
    float* __restrict__ out,
    int Mw, int Nw, int K,
    long aB, long bB, long oB)     // element strides for blockIdx.z
{
    __shared__ u16 smem[4 * 4 * 128 * 8];   // 32 KB: [buf(Ah,Al,Bh,Bl)][plane 4][w 128][8]
    const int t = threadIdx.x;
    const int lane = t & 63;
    const int wid = t >> 6;
    const int wm = wid >> 1, wn = wid & 1;
    const int lk = lane >> 4, lm = lane & 15;
    const int m0 = blockIdx.y * 128, n0 = blockIdx.x * 128;
    const int z = blockIdx.z;
    const u16* pAhi = Ahi + (size_t)z * aB;
    const u16* pAlo = Alo + (size_t)z * aB;
    const u16* pBhi = Bhi + (size_t)z * bB;
    const u16* pBlo = Blo + (size_t)z * bB;

    f32x4 acc[4][4] = {};

    const int nK = K >> 5;
    for (int ks = 0; ks < nK; ++ks) {
        const int kp0 = ks << 2;
        // ---- stage 2048 x 16B chunks (A hi/lo, B hi/lo), linear into LDS ----
        #pragma unroll
        for (int i = 0; i < 8; ++i) {
            const int q = i * 4 + wid;                 // 0..31, wave-uniform
            const int b = q >> 3;                      // buffer id
            const int p = (q & 7) >> 1;                // k-plane
            const int w = ((q & 1) << 6) + lane;       // width index 0..127
            const u16* src;
            if (b == 0)      src = pAhi + ((size_t)(kp0 + p) * Mw + m0 + w) * 8;
            else if (b == 1) src = pAlo + ((size_t)(kp0 + p) * Mw + m0 + w) * 8;
            else if (b == 2) src = pBhi + ((size_t)(kp0 + p) * Nw + n0 + w) * 8;
            else             src = pBlo + ((size_t)(kp0 + p) * Nw + n0 + w) * 8;
            gload16(src, &smem[(size_t)(((b * 4 + p) * 128) + w) * 8]);
        }
        __syncthreads();
        // ---- fragments ----
        short8v ah[4], al[4], bh[4], bl[4];
        #pragma unroll
        for (int f = 0; f < 4; ++f) {
            ah[f] = *(const short8v*)&smem[((0 * 4 + lk) * 128 + wm * 64 + f * 16 + lm) * 8];
            al[f] = *(const short8v*)&smem[((1 * 4 + lk) * 128 + wm * 64 + f * 16 + lm) * 8];
            bh[f] = *(const short8v*)&smem[((2 * 4 + lk) * 128 + wn * 64 + f * 16 + lm) * 8];
            bl[f] = *(const short8v*)&smem[((3 * 4 + lk) * 128 + wn * 64 + f * 16 + lm) * 8];
        }
        #pragma unroll
        for (int i = 0; i < 4; ++i)
            #pragma unroll
            for (int j = 0; j < 4; ++j) {
                acc[i][j] = __builtin_amdgcn_mfma_f32_16x16x32_bf16(ah[i], bh[j], acc[i][j], 0, 0, 0);
                acc[i][j] = __builtin_amdgcn_mfma_f32_16x16x32_bf16(ah[i], bl[j], acc[i][j], 0, 0, 0);
                acc[i][j] = __builtin_amdgcn_mfma_f32_16x16x32_bf16(al[i], bh[j], acc[i][j], 0, 0, 0);
            }
        __syncthreads();
    }
    // ---- epilogue: C/D layout col = lane&15, row = (lane>>4)*4 + reg ----
    float* pout = out + (size_t)z * oB;
    const float* pres = resid + (size_t)z * oB;
    #pragma unroll
    for (int i = 0; i < 4; ++i) {
        #pragma unroll
        for (int r = 0; r < 4; ++r) {
            const int m = m0 + wm * 64 + i * 16 + lk * 4 + r;
            float bv = 0.f;
            if (BIAS) bv = bias[m];
            const size_t ro = (size_t)m * Nw + n0 + wn * 64 + lm;
            #pragma unroll
            for (int j = 0; j < 4; ++j) {
                float v = acc[i][j][r] + bv;
                if (RESID) v += pres[ro + j * 16];
                pout[ro + j * 16] = v;
            }
        }
    }
}

// =====================================================================================
// packB: fp32 [K][N] (batched) -> hi/lo packed [K/8][N][8]. Optional fused exp(x-m)*inv.
// grid: (N/256, K/8, batches)
// =====================================================================================
template<bool EXPSC>
__global__ __launch_bounds__(256) void packB_k(const float* __restrict__ X,
    u16* __restrict__ Hi, u16* __restrict__ Lo,
    const float* __restrict__ mx, const float* __restrict__ inv,
    int Nw, long xB, long pB)
{
    const int n = blockIdx.x * 256 + threadIdx.x;
    const int p = blockIdx.y;
    const int z = blockIdx.z;
    const float* Xp = X + (size_t)z * xB + ((size_t)p * 8) * Nw + n;
    float em = 0.f, ei = 1.f;
    if (EXPSC) { em = mx[n]; ei = inv[n]; }
    u16 hi[8], lo[8];
    #pragma unroll
    for (int j = 0; j < 8; ++j) {
        float v = Xp[(size_t)j * Nw];
        if (EXPSC) v = __expf(v - em) * ei;
        u16 h = f2bf(v);
        hi[j] = h;
        lo[j] = f2bf(v - bf2f(h));
    }
    const size_t o = (size_t)z * pB + ((size_t)p * Nw + n) * 8;
    *(uint4*)&Hi[o] = *(const uint4*)hi;
    *(uint4*)&Lo[o] = *(const uint4*)lo;
}

// =====================================================================================
// packA_T: weight W [M=512][K] fp32 -> transposed packed [K/8][512][8] hi/lo
// grid: (K/64, 512/64)
// =====================================================================================
__global__ __launch_bounds__(256) void packA_T(const float* __restrict__ W,
    u16* __restrict__ Hi, u16* __restrict__ Lo, int Kdim)
{
    __shared__ float tile[64][65];
    const int t = threadIdx.x;
    const int k0 = blockIdx.x * 64, m0 = blockIdx.y * 64;
    const int kk = t & 63, mb = t >> 6;
    #pragma unroll
    for (int it = 0; it < 16; ++it) {
        int mm = mb + it * 4;
        tile[mm][kk] = W[(size_t)(m0 + mm) * Kdim + k0 + kk];
    }
    __syncthreads();
    #pragma unroll
    for (int cc = 0; cc < 2; ++cc) {
        int c = t + cc * 256;
        int kp = c >> 6, m = c & 63;
        u16 hi[8], lo[8];
        #pragma unroll
        for (int j = 0; j < 8; ++j) {
            float v = tile[m][kp * 8 + j];
            u16 h = f2bf(v);
            hi[j] = h;
            lo[j] = f2bf(v - bf2f(h));
        }
        size_t o = ((size_t)(k0 / 8 + kp) * CH + m0 + m) * 8;
        *(uint4*)&Hi[o] = *(const uint4*)hi;
        *(uint4*)&Lo[o] = *(const uint4*)lo;
    }
}

// =====================================================================================
// pack_hvT: Hv fp32 [C][N] (batched) -> HvT packed [N/8][C][8] hi/lo and (Hv^2)T hi/lo
// grid: (N/64, C/64, 2=batch)
// =====================================================================================
__global__ __launch_bounds__(256) void pack_hvT(const float* __restrict__ Hv,
    u16* __restrict__ H1h, u16* __restrict__ H1l,
    u16* __restrict__ H2h, u16* __restrict__ H2l)
{
    __shared__ float tile[64][65];
    const int t = threadIdx.x;
    const int s0 = blockIdx.x * 64, c0 = blockIdx.y * 64;
    const int z = blockIdx.z;
    const float* src = Hv + (size_t)z * CH * NS;
    const int ss = t & 63, cb = t >> 6;
    #pragma unroll
    for (int it = 0; it < 16; ++it) {
        int cc = cb + it * 4;
        tile[cc][ss] = src[(size_t)(c0 + cc) * NS + s0 + ss];
    }
    __syncthreads();
    const size_t zb = (size_t)z * NS * CH;
    #pragma unroll
    for (int cc2 = 0; cc2 < 2; ++cc2) {
        int c = t + cc2 * 256;
        int sp = c >> 6, cm = c & 63;
        u16 h1[8], l1[8], h2[8], l2[8];
        #pragma unroll
        for (int j = 0; j < 8; ++j) {
            float v = tile[cm][sp * 8 + j];
            u16 a = f2bf(v); h1[j] = a; l1[j] = f2bf(v - bf2f(a));
            float v2 = v * v;
            u16 b = f2bf(v2); h2[j] = b; l2[j] = f2bf(v2 - bf2f(b));
        }
        size_t o = zb + ((size_t)(s0 / 8 + sp) * CH + c0 + cm) * 8;
        *(uint4*)&H1h[o] = *(const uint4*)h1;
        *(uint4*)&H1l[o] = *(const uint4*)l1;
        *(uint4*)&H2h[o] = *(const uint4*)h2;
        *(uint4*)&H2l[o] = *(const uint4*)l2;
    }
}

// =====================================================================================
// column softmax stats over S^T [s][n]: online max + sum(exp) per column n
// =====================================================================================
__global__ __launch_bounds__(256) void colstats_part(const float* __restrict__ S,
    float* __restrict__ pm, float* __restrict__ ps)
{
    const int n = blockIdx.x * 256 + threadIdx.x;
    const int s0 = blockIdx.y * 256;
    float m = -3.0e38f, sum = 0.f;
    for (int s = s0; s < s0 + 256; ++s) {
        float x = S[(size_t)s * NS + n];
        float nm = fmaxf(m, x);
        sum = sum * __expf(m - nm) + __expf(x - nm);
        m = nm;
    }
    pm[blockIdx.y * NS + n] = m;
    ps[blockIdx.y * NS + n] = sum;
}

__global__ __launch_bounds__(256) void colstats_comb(const float* __restrict__ pm,
    const float* __restrict__ ps, float* __restrict__ mx, float* __restrict__ inv)
{
    const int n = blockIdx.x * 256 + threadIdx.x;
    float m = -3.0e38f, s = 0.f;
    #pragma unroll
    for (int g = 0; g < 16; ++g) {
        float gm = pm[g * NS + n], gs = ps[g * NS + n];
        float nm = fmaxf(m, gm);
        s = s * __expf(m - nm) + gs * __expf(gm - nm);
        m = nm;
    }
    mx[n] = m;
    inv[n] = 1.f / s;
}

// ================= per-(b,c) content stats =================
__global__ __launch_bounds__(256) void content_stats(const float* __restrict__ content,
                                                     float* __restrict__ cmean,
                                                     float* __restrict__ cinv)
{
    const int bc = blockIdx.x;
    const float4* p = (const float4*)(content + (size_t)bc * NS);
    const int t = threadIdx.x;
    float s = 0.f, s2 = 0.f;
    #pragma unroll
    for (int j = 0; j < 4; ++j) {
        float4 v = p[t + j * 256];
        s  += (v.x + v.y) + (v.z + v.w);
        s2 += (v.x * v.x + v.y * v.y) + (v.z * v.z + v.w * v.w);
    }
    #pragma unroll
    for (int off = 32; off >= 1; off >>= 1) {
        s  += __shfl_xor(s, off);
        s2 += __shfl_xor(s2, off);
    }
    __shared__ float r1[4], r2[4];
    const int wid = t >> 6;
    if ((t & 63) == 0) { r1[wid] = s; r2[wid] = s2; }
    __syncthreads();
    if (t == 0) {
        s  = (r1[0] + r1[1]) + (r1[2] + r1[3]);
        s2 = (r2[0] + r2[1]) + (r2[2] + r2[3]);
        const float mean = s * (1.0f / 4096.f);
        const float var = (s2 - 4096.f * mean * mean) * (1.0f / 4095.f);
        cmean[bc] = mean;
        cinv[bc] = rsqrtf(fmaxf(var, 0.f) + EPSV);
    }
}

// ================= O = sqrt(max(E[x^2]-E[x]^2,0)) * norm(content) + E[x] =================
__global__ __launch_bounds__(256) void compute_O(const float* __restrict__ Mean,
                                                 const float* __restrict__ Sec,
                                                 const float* __restrict__ content,
                                                 const float* __restrict__ cmean,
                                                 const float* __restrict__ cinv,
                                                 float* __restrict__ O)
{
    const int idx = blockIdx.x * 256 + threadIdx.x;
    const int bc = idx >> 10;
    float4 mn = ((const float4*)Mean)[idx];
    float4 sc = ((const float4*)Sec)[idx];
    float4 ct = ((const float4*)content)[idx];
    const float cm = cmean[bc], ci = cinv[bc];
    float4 o;
    o.x = sqrtf(fmaxf(sc.x - mn.x * mn.x, 0.f)) * ((ct.x - cm) * ci) + mn.x;
    o.y = sqrtf(fmaxf(sc.y - mn.y * mn.y, 0.f)) * ((ct.y - cm) * ci) + mn.y;
    o.z = sqrtf(fmaxf(sc.z - mn.z * mn.z, 0.f)) * ((ct.z - cm) * ci) + mn.z;
    o.w = sqrtf(fmaxf(sc.w - mn.w * mn.w, 0.f)) * ((ct.w - cm) * ci) + mn.w;
    ((float4*)O)[idx] = o;
}

// =====================================================================================
extern "C" void kernel_launch(void* const* d_in, const int* in_sizes, int n_in,
                              void* d_out, int out_size, void* d_ws, size_t ws_size,
                              hipStream_t stream)
{
    const float* content = (const float*)d_in[0];
    const float* style   = (const float*)d_in[1];
    const float* f_w   = (const float*)d_in[2];
    const float* f_b   = (const float*)d_in[3];
    const float* g_w   = (const float*)d_in[4];
    const float* g_b   = (const float*)d_in[5];
    const float* h_w   = (const float*)d_in[6];
    const float* h_b   = (const float*)d_in[7];
    const float* out_w = (const float*)d_in[8];
    const float* out_b = (const float*)d_in[9];
    float* out = (float*)d_out;

    char* ws = (char*)d_ws;
    size_t off = 0;
    auto alloc = [&](size_t bytes) -> void* {
        void* p = ws + off;
        off = (off + bytes + 255) & ~(size_t)255;
        return p;
    };

    const size_t KN = (size_t)CH * NS;        // 2,097,152 elements (one batch plane)

    // ---- weight packs: 4 x (hi,lo) of 512x512 bf16 ----
    u16 *Wh[4], *Wl[4];
    for (int w = 0; w < 4; ++w) { Wh[w] = (u16*)alloc(CH * CH * 2); Wl[w] = (u16*)alloc(CH * CH * 2); }

    // ---- R2: one 8*KN u16 region. Two overlapping (time-disjoint) layouts:
    //   phase 1 (conv inputs):  [Xc_hi | Xc_lo | Xs_hi | Xs_lo]          (each 2KN)
    //   phase 2 (PV A-packs):   [HvT_hi | Hv2T_hi | HvT_lo | Hv2T_lo]    (each 2KN)
    //   phase-2 layout makes z-stride 2KN valid for BOTH hi and lo pointers.
    u16* R2 = (u16*)alloc(8 * KN * 2);
    u16* Xc_hi = R2;            u16* Xc_lo = R2 + 2 * KN;
    u16* Xs_hi = R2 + 4 * KN;   u16* Xs_lo = R2 + 6 * KN;
    u16* HvT_hi  = R2;              // z=0 A-hi
    u16* Hv2T_hi = R2 + 2 * KN;     // z=1 A-hi  (= HvT_hi + 2KN)
    u16* HvT_lo  = R2 + 4 * KN;     // z=0 A-lo
    u16* Hv2T_lo = R2 + 6 * KN;     // z=1 A-lo  (= HvT_lo + 2KN)

    // ---- R3: Fq/Gk packs; Gk pack reused as O pack ----
    u16* Fqp_hi = (u16*)alloc(2 * KN * 2);  u16* Fqp_lo = (u16*)alloc(2 * KN * 2);
    u16* Gkp_hi = (u16*)alloc(2 * KN * 2);  u16* Gkp_lo = (u16*)alloc(2 * KN * 2);
    u16* Op_hi = Gkp_hi;  u16* Op_lo = Gkp_lo;     // alias: Gk packs dead after last QK

    // ---- R4: P packs (one batch at a time) ----
    u16* Pp_hi = (u16*)alloc((size_t)NS * NS * 2);
    u16* Pp_lo = (u16*)alloc((size_t)NS * NS * 2);

    // ---- R5: fp32 union: {Fq32,Gk32,Hv32} -> S32 -> O32 (67.2 MB) ----
    char* R5 = (char*)alloc((size_t)NS * NS * 4);
    float* Fq32 = (float*)R5;
    float* Gk32 = (float*)(R5 + 2 * KN * 4);
    float* Hv32 = (float*)(R5 + 4 * KN * 4);
    float* S32  = (float*)R5;                      // after packs of Fq/Gk/Hv
    float* O32  = (float*)R5;                      // after last PV

    // ---- R6: Mean/Sec fp32 (contiguous so PV's z-stride covers Mean->Sec) ----
    float* Mean32 = (float*)alloc(2 * KN * 4);
    float* Sec32  = (float*)alloc(2 * KN * 4);

    // ---- small ----
    float* pm    = (float*)alloc(16 * NS * 4);
    float* ps    = (float*)alloc(16 * NS * 4);
    float* mxv   = (float*)alloc(NS * 4);
    float* invv  = (float*)alloc(NS * 4);
    float* cmean = (float*)alloc(1024 * 4);
    float* cinv  = (float*)alloc(1024 * 4);
    (void)ws_size; (void)in_sizes; (void)n_in; (void)out_size;

    // ================= pipeline =================
    // weight + input packs
    packA_T<<<dim3(8, 8), 256, 0, stream>>>(f_w,   Wh[0], Wl[0], CH);
    packA_T<<<dim3(8, 8), 256, 0, stream>>>(g_w,   Wh[1], Wl[1], CH);
    packA_T<<<dim3(8, 8), 256, 0, stream>>>(h_w,   Wh[2], Wl[2], CH);
    packA_T<<<dim3(8, 8), 256, 0, stream>>>(out_w, Wh[3], Wl[3], CH);
    packB_k<false><<<dim3(16, 64, 2), 256, 0, stream>>>(content, Xc_hi, Xc_lo, nullptr, nullptr, NS, (long)KN, (long)KN);
    packB_k<false><<<dim3(16, 64, 2), 256, 0, stream>>>(style,   Xs_hi, Xs_lo, nullptr, nullptr, NS, (long)KN, (long)KN);
    content_stats<<<1024, 256, 0, stream>>>(content, cmean, cinv);

    // convs (fp32 out, bias)
    gemm_split<true, false><<<dim3(32, 4, 2), 256, 0, stream>>>(
        Wh[0], Wl[0], Xc_hi, Xc_lo, f_b, nullptr, Fq32, CH, NS, CH, 0, (long)KN, (long)KN);
    gemm_split<true, false><<<dim3(32, 4, 2), 256, 0, stream>>>(
        Wh[1], Wl[1], Xs_hi, Xs_lo, g_b, nullptr, Gk32, CH, NS, CH, 0, (long)KN, (long)KN);
    gemm_split<true, false><<<dim3(32, 4, 2), 256, 0, stream>>>(
        Wh[2], Wl[2], Xs_hi, Xs_lo, h_b, nullptr, Hv32, CH, NS, CH, 0, (long)KN, (long)KN);

    // re-pack conv outputs for attention GEMMs
    packB_k<false><<<dim3(16, 64, 2), 256, 0, stream>>>(Fq32, Fqp_hi, Fqp_lo, nullptr, nullptr, NS, (long)KN, (long)KN);
    packB_k<false><<<dim3(16, 64, 2), 256, 0, stream>>>(Gk32, Gkp_hi, Gkp_lo, nullptr, nullptr, NS, (long)KN, (long)KN);
    // NOTE: overwrites R2 (Xc/Xs packs dead by now) with phase-2 layout
    pack_hvT<<<dim3(64, 8, 2), 256, 0, stream>>>(Hv32, HvT_hi, HvT_lo, Hv2T_hi, Hv2T_lo);

    for (int b = 0; b < 2; ++b) {
        const size_t bo = (size_t)b * KN;
        // QK^T: S^T[s][n] = sum_k Gk[k][s] * Fq[k][n]   (M = s = 4096)
        gemm_split<false, false><<<dim3(32, 32, 1), 256, 0, stream>>>(
            Gkp_hi + bo, Gkp_lo + bo, Fqp_hi + bo, Fqp_lo + bo, nullptr, nullptr,
            S32, NS, NS, CH, 0, 0, 0);
        // column softmax stats + fused exp/scale pack
        colstats_part<<<dim3(16, 16), 256, 0, stream>>>(S32, pm, ps);
        colstats_comb<<<16, 256, 0, stream>>>(pm, ps, mxv, invv);
        packB_k<true><<<dim3(16, 512, 1), 256, 0, stream>>>(S32, Pp_hi, Pp_lo, mxv, invv, NS, 0, 0);
        // PV: z=0 -> Mean (A=HvT), z=1 -> Sec (A=Hv2T); A z-stride = 2*KN elements, out z-stride = 2*KN floats
        gemm_split<false, false><<<dim3(32, 4, 2), 256, 0, stream>>>(
            HvT_hi + bo, HvT_lo + bo, Pp_hi, Pp_lo, nullptr, nullptr,
            Mean32 + bo, CH, NS, NS, (long)(2 * KN), 0, (long)(2 * KN));
    }

    compute_O<<<4096, 256, 0, stream>>>(Mean32, Sec32, content, cmean, cinv, O32);
    packB_k<false><<<dim3(16, 64, 2), 256, 0, stream>>>(O32, Op_hi, Op_lo, nullptr, nullptr, NS, (long)KN, (long)KN);
    // out conv: bias + residual(content) -> d_out
    gemm_split<true, true><<<dim3(32, 4, 2), 256, 0, stream>>>(
        Wh[3], Wl[3], Op_hi, Op_lo, out_b, content, out, CH, NS, CH, 0, (long)KN, (long)KN);
}

// Round 4
// 535.410 us; speedup vs baseline: 3.0156x; 1.1614x over previous
//
#include <hip/hip_runtime.h>
#include <math.h>

#define NS 4096
#define CH 512
#define EPSV 1e-5f

typedef __attribute__((ext_vector_type(8))) short short8v;   // 8 x bf16 MFMA operand
typedef __attribute__((ext_vector_type(4))) float f32x4;     // MFMA accumulator
typedef unsigned short u16;

// ---------- bf16 helpers (RNE) ----------
__device__ __forceinline__ u16 f2bf(float x) {
    unsigned u = __float_as_uint(x);
    u += 0x7fff + ((u >> 16) & 1);
    return (u16)(u >> 16);
}
__device__ __forceinline__ float bf2f(u16 b) { return __uint_as_float(((unsigned)b) << 16); }

// ---------- async global->LDS, 16B per lane ----------
__device__ __forceinline__ void gload16(const void* g, void* l) {
    __builtin_amdgcn_global_load_lds((const __attribute__((address_space(1))) unsigned*)g,
                                     (__attribute__((address_space(3))) unsigned*)l, 16, 0, 0);
}

// =====================================================================================
// Generic split-bf16 GEMM:  out[m][n] = sum_k (Ahi+Alo)[k][m] * (Bhi+Blo)[k][n]  (+bias[m]) (+resid)
// A,B packed layout: element (k, x) at ((k>>3)*W + x)*8 + (k&7)   (W = Mw for A, Nw for B)
// Tile 128x128, BK=32, 4 waves (2x2), per-wave 64x64 via 4x4 frags of 16x16x32.
// 3 MFMA terms per fragment pair: hh + hl + lh  (lo*lo negligible).
// 2-phase double-buffered pipeline (T3-minimum): prefetch K-tile t+1 into buf^1
// BEFORE computing tile t; the compiler's vmcnt(0)-before-barrier then drains after
// ~250 cycles of MFMA instead of immediately.
// =====================================================================================
template<bool BIAS, bool RESID>
__global__ __launch_bounds__(256, 2) void gemm_split(
    const u16* __restrict__ Ahi, const u16* __restrict__ Alo,
    const u16* __restrict__ Bhi, const u16* __restrict__ Blo,
    const float* __restrict__ bias, const float* __restrict__ resid,
    float* __restrict__ out,
    int Mw, int Nw, int K,
    long aB, long bB, long oB)     // element strides for blockIdx.z
{
    __shared__ u16 smem[2][4 * 4 * 128 * 8];   // 2 x 32 KB double buffer
    const int t = threadIdx.x;
    const int lane = t & 63;
    const int wid = t >> 6;
    const int wm = wid >> 1, wn = wid & 1;
    const int lk = lane >> 4, lm = lane & 15;
    const int m0 = blockIdx.y * 128, n0 = blockIdx.x * 128;
    const int z = blockIdx.z;
    const u16* pAhi = Ahi + (size_t)z * aB;
    const u16* pAlo = Alo + (size_t)z * aB;
    const u16* pBhi = Bhi + (size_t)z * bB;
    const u16* pBlo = Blo + (size_t)z * bB;

    f32x4 acc[4][4] = {};

    // stage K-tile ks into LDS buffer buf (8 x 16B chunks per thread)
    auto stage = [&](int buf, int ks) {
        const int kp0 = ks << 2;
        #pragma unroll
        for (int i = 0; i < 8; ++i) {
            const int q = i * 4 + wid;                 // 0..31, wave-uniform
            const int b = q >> 3;                      // buffer id
            const int p = (q & 7) >> 1;                // k-plane
            const int w = ((q & 1) << 6) + lane;       // width index 0..127
            const u16* src;
            if (b == 0)      src = pAhi + ((size_t)(kp0 + p) * Mw + m0 + w) * 8;
            else if (b == 1) src = pAlo + ((size_t)(kp0 + p) * Mw + m0 + w) * 8;
            else if (b == 2) src = pBhi + ((size_t)(kp0 + p) * Nw + n0 + w) * 8;
            else             src = pBlo + ((size_t)(kp0 + p) * Nw + n0 + w) * 8;
            gload16(src, &smem[buf][(size_t)(((b * 4 + p) * 128) + w) * 8]);
        }
    };

    const int nK = K >> 5;
    stage(0, 0);
    __syncthreads();                 // drains vmcnt(0): buf0 ready
    int cur = 0;
    for (int ks = 0; ks < nK; ++ks) {
        if (ks + 1 < nK) stage(cur ^ 1, ks + 1);   // prefetch next tile (in flight during MFMA)
        // ---- fragments from current buffer ----
        const u16* sm = smem[cur];
        short8v ah[4], al[4], bh[4], bl[4];
        #pragma unroll
        for (int f = 0; f < 4; ++f) {
            ah[f] = *(const short8v*)&sm[((0 * 4 + lk) * 128 + wm * 64 + f * 16 + lm) * 8];
            al[f] = *(const short8v*)&sm[((1 * 4 + lk) * 128 + wm * 64 + f * 16 + lm) * 8];
            bh[f] = *(const short8v*)&sm[((2 * 4 + lk) * 128 + wn * 64 + f * 16 + lm) * 8];
            bl[f] = *(const short8v*)&sm[((3 * 4 + lk) * 128 + wn * 64 + f * 16 + lm) * 8];
        }
        #pragma unroll
        for (int i = 0; i < 4; ++i)
            #pragma unroll
            for (int j = 0; j < 4; ++j) {
                acc[i][j] = __builtin_amdgcn_mfma_f32_16x16x32_bf16(ah[i], bh[j], acc[i][j], 0, 0, 0);
                acc[i][j] = __builtin_amdgcn_mfma_f32_16x16x32_bf16(ah[i], bl[j], acc[i][j], 0, 0, 0);
                acc[i][j] = __builtin_amdgcn_mfma_f32_16x16x32_bf16(al[i], bh[j], acc[i][j], 0, 0, 0);
            }
        __syncthreads();             // drains vmcnt(0): prefetched buffer complete, reads done
        cur ^= 1;
    }
    // ---- epilogue: C/D layout col = lane&15, row = (lane>>4)*4 + reg ----
    float* pout = out + (size_t)z * oB;
    const float* pres = resid + (size_t)z * oB;
    #pragma unroll
    for (int i = 0; i < 4; ++i) {
        #pragma unroll
        for (int r = 0; r < 4; ++r) {
            const int m = m0 + wm * 64 + i * 16 + lk * 4 + r;
            float bv = 0.f;
            if (BIAS) bv = bias[m];
            const size_t ro = (size_t)m * Nw + n0 + wn * 64 + lm;
            #pragma unroll
            for (int j = 0; j < 4; ++j) {
                float v = acc[i][j][r] + bv;
                if (RESID) v += pres[ro + j * 16];
                pout[ro + j * 16] = v;
            }
        }
    }
}

// =====================================================================================
// packB: fp32 [K][N] (batched) -> hi/lo packed [K/8][N][8]. Optional fused exp(x-m)*inv.
// grid: (N/256, K/8, batches)
// =====================================================================================
template<bool EXPSC>
__global__ __launch_bounds__(256) void packB_k(const float* __restrict__ X,
    u16* __restrict__ Hi, u16* __restrict__ Lo,
    const float* __restrict__ mx, const float* __restrict__ inv,
    int Nw, long xB, long pB)
{
    const int n = blockIdx.x * 256 + threadIdx.x;
    const int p = blockIdx.y;
    const int z = blockIdx.z;
    const float* Xp = X + (size_t)z * xB + ((size_t)p * 8) * Nw + n;
    float em = 0.f, ei = 1.f;
    if (EXPSC) { em = mx[n]; ei = inv[n]; }
    u16 hi[8], lo[8];
    #pragma unroll
    for (int j = 0; j < 8; ++j) {
        float v = Xp[(size_t)j * Nw];
        if (EXPSC) v = __expf(v - em) * ei;
        u16 h = f2bf(v);
        hi[j] = h;
        lo[j] = f2bf(v - bf2f(h));
    }
    const size_t o = (size_t)z * pB + ((size_t)p * Nw + n) * 8;
    *(uint4*)&Hi[o] = *(const uint4*)hi;
    *(uint4*)&Lo[o] = *(const uint4*)lo;
}

// =====================================================================================
// packA_T: weight W [M=512][K] fp32 -> transposed packed [K/8][512][8] hi/lo
// grid: (K/64, 512/64)
// =====================================================================================
__global__ __launch_bounds__(256) void packA_T(const float* __restrict__ W,
    u16* __restrict__ Hi, u16* __restrict__ Lo, int Kdim)
{
    __shared__ float tile[64][65];
    const int t = threadIdx.x;
    const int k0 = blockIdx.x * 64, m0 = blockIdx.y * 64;
    const int kk = t & 63, mb = t >> 6;
    #pragma unroll
    for (int it = 0; it < 16; ++it) {
        int mm = mb + it * 4;
        tile[mm][kk] = W[(size_t)(m0 + mm) * Kdim + k0 + kk];
    }
    __syncthreads();
    #pragma unroll
    for (int cc = 0; cc < 2; ++cc) {
        int c = t + cc * 256;
        int kp = c >> 6, m = c & 63;
        u16 hi[8], lo[8];
        #pragma unroll
        for (int j = 0; j < 8; ++j) {
            float v = tile[m][kp * 8 + j];
            u16 h = f2bf(v);
            hi[j] = h;
            lo[j] = f2bf(v - bf2f(h));
        }
        size_t o = ((size_t)(k0 / 8 + kp) * CH + m0 + m) * 8;
        *(uint4*)&Hi[o] = *(const uint4*)hi;
        *(uint4*)&Lo[o] = *(const uint4*)lo;
    }
}

// =====================================================================================
// pack_hvT: Hv fp32 [C][N] (batched) -> HvT packed [N/8][C][8] hi/lo and (Hv^2)T hi/lo
// grid: (N/64, C/64, 2=batch)
// =====================================================================================
__global__ __launch_bounds__(256) void pack_hvT(const float* __restrict__ Hv,
    u16* __restrict__ H1h, u16* __restrict__ H1l,
    u16* __restrict__ H2h, u16* __restrict__ H2l)
{
    __shared__ float tile[64][65];
    const int t = threadIdx.x;
    const int s0 = blockIdx.x * 64, c0 = blockIdx.y * 64;
    const int z = blockIdx.z;
    const float* src = Hv + (size_t)z * CH * NS;
    const int ss = t & 63, cb = t >> 6;
    #pragma unroll
    for (int it = 0; it < 16; ++it) {
        int cc = cb + it * 4;
        tile[cc][ss] = src[(size_t)(c0 + cc) * NS + s0 + ss];
    }
    __syncthreads();
    const size_t zb = (size_t)z * NS * CH;
    #pragma unroll
    for (int cc2 = 0; cc2 < 2; ++cc2) {
        int c = t + cc2 * 256;
        int sp = c >> 6, cm = c & 63;
        u16 h1[8], l1[8], h2[8], l2[8];
        #pragma unroll
        for (int j = 0; j < 8; ++j) {
            float v = tile[cm][sp * 8 + j];
            u16 a = f2bf(v); h1[j] = a; l1[j] = f2bf(v - bf2f(a));
            float v2 = v * v;
            u16 b = f2bf(v2); h2[j] = b; l2[j] = f2bf(v2 - bf2f(b));
        }
        size_t o = zb + ((size_t)(s0 / 8 + sp) * CH + c0 + cm) * 8;
        *(uint4*)&H1h[o] = *(const uint4*)h1;
        *(uint4*)&H1l[o] = *(const uint4*)l1;
        *(uint4*)&H2h[o] = *(const uint4*)h2;
        *(uint4*)&H2l[o] = *(const uint4*)l2;
    }
}

// =====================================================================================
// column softmax stats over S^T [s][n]: online max + sum(exp) per column n
// =====================================================================================
__global__ __launch_bounds__(256) void colstats_part(const float* __restrict__ S,
    float* __restrict__ pm, float* __restrict__ ps)
{
    const int n = blockIdx.x * 256 + threadIdx.x;
    const int s0 = blockIdx.y * 256;
    float m = -3.0e38f, sum = 0.f;
    for (int s = s0; s < s0 + 256; ++s) {
        float x = S[(size_t)s * NS + n];
        float nm = fmaxf(m, x);
        sum = sum * __expf(m - nm) + __expf(x - nm);
        m = nm;
    }
    pm[blockIdx.y * NS + n] = m;
    ps[blockIdx.y * NS + n] = sum;
}

__global__ __launch_bounds__(256) void colstats_comb(const float* __restrict__ pm,
    const float* __restrict__ ps, float* __restrict__ mx, float* __restrict__ inv)
{
    const int n = blockIdx.x * 256 + threadIdx.x;
    float m = -3.0e38f, s = 0.f;
    #pragma unroll
    for (int g = 0; g < 16; ++g) {
        float gm = pm[g * NS + n], gs = ps[g * NS + n];
        float nm = fmaxf(m, gm);
        s = s * __expf(m - nm) + gs * __expf(gm - nm);
        m = nm;
    }
    mx[n] = m;
    inv[n] = 1.f / s;
}

// ================= per-(b,c) content stats =================
__global__ __launch_bounds__(256) void content_stats(const float* __restrict__ content,
                                                     float* __restrict__ cmean,
                                                     float* __restrict__ cinv)
{
    const int bc = blockIdx.x;
    const float4* p = (const float4*)(content + (size_t)bc * NS);
    const int t = threadIdx.x;
    float s = 0.f, s2 = 0.f;
    #pragma unroll
    for (int j = 0; j < 4; ++j) {
        float4 v = p[t + j * 256];
        s  += (v.x + v.y) + (v.z + v.w);
        s2 += (v.x * v.x + v.y * v.y) + (v.z * v.z + v.w * v.w);
    }
    #pragma unroll
    for (int off = 32; off >= 1; off >>= 1) {
        s  += __shfl_xor(s, off);
        s2 += __shfl_xor(s2, off);
    }
    __shared__ float r1[4], r2[4];
    const int wid = t >> 6;
    if ((t & 63) == 0) { r1[wid] = s; r2[wid] = s2; }
    __syncthreads();
    if (t == 0) {
        s  = (r1[0] + r1[1]) + (r1[2] + r1[3]);
        s2 = (r2[0] + r2[1]) + (r2[2] + r2[3]);
        const float mean = s * (1.0f / 4096.f);
        const float var = (s2 - 4096.f * mean * mean) * (1.0f / 4095.f);
        cmean[bc] = mean;
        cinv[bc] = rsqrtf(fmaxf(var, 0.f) + EPSV);
    }
}

// ================= O = sqrt(max(E[x^2]-E[x]^2,0)) * norm(content) + E[x] =================
__global__ __launch_bounds__(256) void compute_O(const float* __restrict__ Mean,
                                                 const float* __restrict__ Sec,
                                                 const float* __restrict__ content,
                                                 const float* __restrict__ cmean,
                                                 const float* __restrict__ cinv,
                                                 float* __restrict__ O)
{
    const int idx = blockIdx.x * 256 + threadIdx.x;
    const int bc = idx >> 10;
    float4 mn = ((const float4*)Mean)[idx];
    float4 sc = ((const float4*)Sec)[idx];
    float4 ct = ((const float4*)content)[idx];
    const float cm = cmean[bc], ci = cinv[bc];
    float4 o;
    o.x = sqrtf(fmaxf(sc.x - mn.x * mn.x, 0.f)) * ((ct.x - cm) * ci) + mn.x;
    o.y = sqrtf(fmaxf(sc.y - mn.y * mn.y, 0.f)) * ((ct.y - cm) * ci) + mn.y;
    o.z = sqrtf(fmaxf(sc.z - mn.z * mn.z, 0.f)) * ((ct.z - cm) * ci) + mn.z;
    o.w = sqrtf(fmaxf(sc.w - mn.w * mn.w, 0.f)) * ((ct.w - cm) * ci) + mn.w;
    ((float4*)O)[idx] = o;
}

// =====================================================================================
extern "C" void kernel_launch(void* const* d_in, const int* in_sizes, int n_in,
                              void* d_out, int out_size, void* d_ws, size_t ws_size,
                              hipStream_t stream)
{
    const float* content = (const float*)d_in[0];
    const float* style   = (const float*)d_in[1];
    const float* f_w   = (const float*)d_in[2];
    const float* f_b   = (const float*)d_in[3];
    const float* g_w   = (const float*)d_in[4];
    const float* g_b   = (const float*)d_in[5];
    const float* h_w   = (const float*)d_in[6];
    const float* h_b   = (const float*)d_in[7];
    const float* out_w = (const float*)d_in[8];
    const float* out_b = (const float*)d_in[9];
    float* out = (float*)d_out;

    char* ws = (char*)d_ws;
    size_t off = 0;
    auto alloc = [&](size_t bytes) -> void* {
        void* p = ws + off;
        off = (off + bytes + 255) & ~(size_t)255;
        return p;
    };

    const size_t KN = (size_t)CH * NS;        // 2,097,152 elements (one batch plane)

    // ---- weight packs: 4 x (hi,lo) of 512x512 bf16 ----
    u16 *Wh[4], *Wl[4];
    for (int w = 0; w < 4; ++w) { Wh[w] = (u16*)alloc(CH * CH * 2); Wl[w] = (u16*)alloc(CH * CH * 2); }

    // ---- R2: one 8*KN u16 region. Two overlapping (time-disjoint) layouts:
    //   phase 1 (conv inputs):  [Xc_hi | Xc_lo | Xs_hi | Xs_lo]          (each 2KN)
    //   phase 2 (PV A-packs):   [HvT_hi | Hv2T_hi | HvT_lo | Hv2T_lo]    (each 2KN)
    //   phase-2 layout makes z-stride 2KN valid for BOTH hi and lo pointers.
    u16* R2 = (u16*)alloc(8 * KN * 2);
    u16* Xc_hi = R2;            u16* Xc_lo = R2 + 2 * KN;
    u16* Xs_hi = R2 + 4 * KN;   u16* Xs_lo = R2 + 6 * KN;
    u16* HvT_hi  = R2;              // z=0 A-hi
    u16* Hv2T_hi = R2 + 2 * KN;     // z=1 A-hi  (= HvT_hi + 2KN)
    u16* HvT_lo  = R2 + 4 * KN;     // z=0 A-lo
    u16* Hv2T_lo = R2 + 6 * KN;     // z=1 A-lo  (= HvT_lo + 2KN)

    // ---- R3: Fq/Gk packs; Gk pack reused as O pack ----
    u16* Fqp_hi = (u16*)alloc(2 * KN * 2);  u16* Fqp_lo = (u16*)alloc(2 * KN * 2);
    u16* Gkp_hi = (u16*)alloc(2 * KN * 2);  u16* Gkp_lo = (u16*)alloc(2 * KN * 2);
    u16* Op_hi = Gkp_hi;  u16* Op_lo = Gkp_lo;     // alias: Gk packs dead after last QK

    // ---- R4: P packs (one batch at a time) ----
    u16* Pp_hi = (u16*)alloc((size_t)NS * NS * 2);
    u16* Pp_lo = (u16*)alloc((size_t)NS * NS * 2);

    // ---- R5: fp32 union: {Fq32,Gk32,Hv32} -> S32 -> O32 (67.2 MB) ----
    char* R5 = (char*)alloc((size_t)NS * NS * 4);
    float* Fq32 = (float*)R5;
    float* Gk32 = (float*)(R5 + 2 * KN * 4);
    float* Hv32 = (float*)(R5 + 4 * KN * 4);
    float* S32  = (float*)R5;                      // after packs of Fq/Gk/Hv
    float* O32  = (float*)R5;                      // after last PV

    // ---- R6: Mean/Sec fp32 (contiguous so PV's z-stride covers Mean->Sec) ----
    float* Mean32 = (float*)alloc(2 * KN * 4);
    float* Sec32  = (float*)alloc(2 * KN * 4);

    // ---- small ----
    float* pm    = (float*)alloc(16 * NS * 4);
    float* ps    = (float*)alloc(16 * NS * 4);
    float* mxv   = (float*)alloc(NS * 4);
    float* invv  = (float*)alloc(NS * 4);
    float* cmean = (float*)alloc(1024 * 4);
    float* cinv  = (float*)alloc(1024 * 4);
    (void)ws_size; (void)in_sizes; (void)n_in; (void)out_size;

    // ================= pipeline =================
    // weight + input packs
    packA_T<<<dim3(8, 8), 256, 0, stream>>>(f_w,   Wh[0], Wl[0], CH);
    packA_T<<<dim3(8, 8), 256, 0, stream>>>(g_w,   Wh[1], Wl[1], CH);
    packA_T<<<dim3(8, 8), 256, 0, stream>>>(h_w,   Wh[2], Wl[2], CH);
    packA_T<<<dim3(8, 8), 256, 0, stream>>>(out_w, Wh[3], Wl[3], CH);
    packB_k<false><<<dim3(16, 64, 2), 256, 0, stream>>>(content, Xc_hi, Xc_lo, nullptr, nullptr, NS, (long)KN, (long)KN);
    packB_k<false><<<dim3(16, 64, 2), 256, 0, stream>>>(style,   Xs_hi, Xs_lo, nullptr, nullptr, NS, (long)KN, (long)KN);
    content_stats<<<1024, 256, 0, stream>>>(content, cmean, cinv);

    // convs (fp32 out, bias)
    gemm_split<true, false><<<dim3(32, 4, 2), 256, 0, stream>>>(
        Wh[0], Wl[0], Xc_hi, Xc_lo, f_b, nullptr, Fq32, CH, NS, CH, 0, (long)KN, (long)KN);
    gemm_split<true, false><<<dim3(32, 4, 2), 256, 0, stream>>>(
        Wh[1], Wl[1], Xs_hi, Xs_lo, g_b, nullptr, Gk32, CH, NS, CH, 0, (long)KN, (long)KN);
    gemm_split<true, false><<<dim3(32, 4, 2), 256, 0, stream>>>(
        Wh[2], Wl[2], Xs_hi, Xs_lo, h_b, nullptr, Hv32, CH, NS, CH, 0, (long)KN, (long)KN);

    // re-pack conv outputs for attention GEMMs
    packB_k<false><<<dim3(16, 64, 2), 256, 0, stream>>>(Fq32, Fqp_hi, Fqp_lo, nullptr, nullptr, NS, (long)KN, (long)KN);
    packB_k<false><<<dim3(16, 64, 2), 256, 0, stream>>>(Gk32, Gkp_hi, Gkp_lo, nullptr, nullptr, NS, (long)KN, (long)KN);
    // NOTE: overwrites R2 (Xc/Xs packs dead by now) with phase-2 layout
    pack_hvT<<<dim3(64, 8, 2), 256, 0, stream>>>(Hv32, HvT_hi, HvT_lo, Hv2T_hi, Hv2T_lo);

    for (int b = 0; b < 2; ++b) {
        const size_t bo = (size_t)b * KN;
        // QK^T: S^T[s][n] = sum_k Gk[k][s] * Fq[k][n]   (M = s = 4096)
        gemm_split<false, false><<<dim3(32, 32, 1), 256, 0, stream>>>(
            Gkp_hi + bo, Gkp_lo + bo, Fqp_hi + bo, Fqp_lo + bo, nullptr, nullptr,
            S32, NS, NS, CH, 0, 0, 0);
        // column softmax stats + fused exp/scale pack
        colstats_part<<<dim3(16, 16), 256, 0, stream>>>(S32, pm, ps);
        colstats_comb<<<16, 256, 0, stream>>>(pm, ps, mxv, invv);
        packB_k<true><<<dim3(16, 512, 1), 256, 0, stream>>>(S32, Pp_hi, Pp_lo, mxv, invv, NS, 0, 0);
        // PV: z=0 -> Mean (A=HvT), z=1 -> Sec (A=Hv2T); A z-stride = 2*KN elements, out z-stride = 2*KN floats
        gemm_split<false, false><<<dim3(32, 4, 2), 256, 0, stream>>>(
            HvT_hi + bo, HvT_lo + bo, Pp_hi, Pp_lo, nullptr, nullptr,
            Mean32 + bo, CH, NS, NS, (long)(2 * KN), 0, (long)(2 * KN));
    }

    compute_O<<<4096, 256, 0, stream>>>(Mean32, Sec32, content, cmean, cinv, O32);
    packB_k<false><<<dim3(16, 64, 2), 256, 0, stream>>>(O32, Op_hi, Op_lo, nullptr, nullptr, NS, (long)KN, (long)KN);
    // out conv: bias + residual(content) -> d_out
    gemm_split<true, true><<<dim3(32, 4, 2), 256, 0, stream>>>(
        Wh[3], Wl[3], Op_hi, Op_lo, out_b, content, out, CH, NS, CH, 0, (long)KN, (long)KN);
}

// Round 5
// 491.041 us; speedup vs baseline: 3.2880x; 1.0904x over previous
//
#include <hip/hip_runtime.h>
#include <math.h>

#define NS 4096
#define CH 512
#define EPSV 1e-5f

typedef __attribute__((ext_vector_type(8))) _Float16 f16x8;  // 8 x fp16 MFMA operand
typedef __attribute__((ext_vector_type(4))) float f32x4;     // MFMA accumulator
typedef unsigned short u16;

// ---------- fp16 helpers (RNE via cast) ----------
__device__ __forceinline__ u16 f2h(float x) {
    _Float16 h = (_Float16)x;
    return __builtin_bit_cast(unsigned short, h);
}
__device__ __forceinline__ float h2f(u16 b) {
    return (float)__builtin_bit_cast(_Float16, b);
}

// ---------- async global->LDS, 16B per lane ----------
__device__ __forceinline__ void gload16(const void* g, void* l) {
    __builtin_amdgcn_global_load_lds((const __attribute__((address_space(1))) unsigned*)g,
                                     (__attribute__((address_space(3))) unsigned*)l, 16, 0, 0);
}

// =====================================================================================
// Split-fp16 GEMM:  out[m][n] = sum_k A[k][m] * B[k][n]  (+bias[m]) (+resid)
//   NP=4: A = Ahi+Alo, B = Bhi+Blo; 3 MFMA terms (hh + hl + lh), ll ~2^-22 dropped.
//   NP=3: A = Ahi+Alo, B = Bhi only; 2 MFMA terms. (used for PV: B=P, correlated-error safe)
// Packed layout: element (k, x) at ((k>>3)*W + x)*8 + (k&7)   (W = Mw for A, Nw for B)
// Tile 128x128, BK=32, 4 waves (2x2), per-wave 64x64 via 4x4 frags of 16x16x32.
// 2-phase double-buffered pipeline: prefetch K-tile t+1 before computing tile t.
// =====================================================================================
template<int NP, bool BIAS, bool RESID>
__global__ __launch_bounds__(256, (NP == 3 ? 3 : 2)) void gemm_split(
    const u16* __restrict__ Ahi, const u16* __restrict__ Alo,
    const u16* __restrict__ Bhi, const u16* __restrict__ Blo,
    const float* __restrict__ bias, const float* __restrict__ resid,
    float* __restrict__ out,
    int Mw, int Nw, int K,
    long aB, long bB, long oB)     // element strides for blockIdx.z
{
    __shared__ u16 smem[2][NP * 4 * 128 * 8];   // 2 x (NP*8KB) double buffer
    const int t = threadIdx.x;
    const int lane = t & 63;
    const int wid = t >> 6;
    const int wm = wid >> 1, wn = wid & 1;
    const int lk = lane >> 4, lm = lane & 15;
    const int m0 = blockIdx.y * 128, n0 = blockIdx.x * 128;
    const int z = blockIdx.z;
    const u16* pAhi = Ahi + (size_t)z * aB;
    const u16* pAlo = Alo + (size_t)z * aB;
    const u16* pBhi = Bhi + (size_t)z * bB;
    const u16* pBlo = (NP == 4) ? (Blo + (size_t)z * bB) : nullptr;

    f32x4 acc[4][4] = {};

    // stage K-tile ks into LDS buffer buf (2*NP x 16B chunks per thread)
    auto stage = [&](int buf, int ks) {
        const int kp0 = ks << 2;
        #pragma unroll
        for (int i = 0; i < 2 * NP; ++i) {
            const int q = i * 4 + wid;                 // wave-uniform
            const int b = q >> 3;                      // plane id
            const int p = (q & 7) >> 1;                // k-plane
            const int w = ((q & 1) << 6) + lane;       // width index 0..127
            const u16* src;
            if (b == 0)      src = pAhi + ((size_t)(kp0 + p) * Mw + m0 + w) * 8;
            else if (b == 1) src = pAlo + ((size_t)(kp0 + p) * Mw + m0 + w) * 8;
            else if (b == 2) src = pBhi + ((size_t)(kp0 + p) * Nw + n0 + w) * 8;
            else             src = pBlo + ((size_t)(kp0 + p) * Nw + n0 + w) * 8;
            gload16(src, &smem[buf][(size_t)(((b * 4 + p) * 128) + w) * 8]);
        }
    };

    const int nK = K >> 5;
    stage(0, 0);
    __syncthreads();                 // drains vmcnt(0): buf0 ready
    int cur = 0;
    for (int ks = 0; ks < nK; ++ks) {
        if (ks + 1 < nK) stage(cur ^ 1, ks + 1);   // prefetch next tile (in flight during MFMA)
        const u16* sm = smem[cur];
        f16x8 ah[4], al[4], bh[4], bl[4];
        #pragma unroll
        for (int f = 0; f < 4; ++f) {
            ah[f] = *(const f16x8*)&sm[((0 * 4 + lk) * 128 + wm * 64 + f * 16 + lm) * 8];
            al[f] = *(const f16x8*)&sm[((1 * 4 + lk) * 128 + wm * 64 + f * 16 + lm) * 8];
            bh[f] = *(const f16x8*)&sm[((2 * 4 + lk) * 128 + wn * 64 + f * 16 + lm) * 8];
            if (NP == 4)
                bl[f] = *(const f16x8*)&sm[((3 * 4 + lk) * 128 + wn * 64 + f * 16 + lm) * 8];
        }
        #pragma unroll
        for (int i = 0; i < 4; ++i)
            #pragma unroll
            for (int j = 0; j < 4; ++j) {
                acc[i][j] = __builtin_amdgcn_mfma_f32_16x16x32_f16(ah[i], bh[j], acc[i][j], 0, 0, 0);
                if (NP == 4)
                    acc[i][j] = __builtin_amdgcn_mfma_f32_16x16x32_f16(ah[i], bl[j], acc[i][j], 0, 0, 0);
                acc[i][j] = __builtin_amdgcn_mfma_f32_16x16x32_f16(al[i], bh[j], acc[i][j], 0, 0, 0);
            }
        __syncthreads();             // prefetched buffer complete, reads done
        cur ^= 1;
    }
    // ---- epilogue: C/D layout col = lane&15, row = (lane>>4)*4 + reg ----
    float* pout = out + (size_t)z * oB;
    const float* pres = resid + (size_t)z * oB;
    #pragma unroll
    for (int i = 0; i < 4; ++i) {
        #pragma unroll
        for (int r = 0; r < 4; ++r) {
            const int m = m0 + wm * 64 + i * 16 + lk * 4 + r;
            float bv = 0.f;
            if (BIAS) bv = bias[m];
            const size_t ro = (size_t)m * Nw + n0 + wn * 64 + lm;
            #pragma unroll
            for (int j = 0; j < 4; ++j) {
                float v = acc[i][j][r] + bv;
                if (RESID) v += pres[ro + j * 16];
                pout[ro + j * 16] = v;
            }
        }
    }
}

// =====================================================================================
// packB: fp32 [K][N] (batched) -> fp16 hi(/lo) packed [K/8][N][8]. Optional fused exp.
// grid: (N/256, K/8, batches)
// =====================================================================================
template<bool EXPSC, bool WLO>
__global__ __launch_bounds__(256) void packB_k(const float* __restrict__ X,
    u16* __restrict__ Hi, u16* __restrict__ Lo,
    const float* __restrict__ mx, const float* __restrict__ inv,
    int Nw, long xB, long pB)
{
    const int n = blockIdx.x * 256 + threadIdx.x;
    const int p = blockIdx.y;
    const int z = blockIdx.z;
    const float* Xp = X + (size_t)z * xB + ((size_t)p * 8) * Nw + n;
    float em = 0.f, ei = 1.f;
    if (EXPSC) { em = mx[n]; ei = inv[n]; }
    u16 hi[8], lo[8];
    #pragma unroll
    for (int j = 0; j < 8; ++j) {
        float v = Xp[(size_t)j * Nw];
        if (EXPSC) v = __expf(v - em) * ei;
        u16 h = f2h(v);
        hi[j] = h;
        if (WLO) lo[j] = f2h(v - h2f(h));
    }
    const size_t o = (size_t)z * pB + ((size_t)p * Nw + n) * 8;
    *(uint4*)&Hi[o] = *(const uint4*)hi;
    if (WLO) *(uint4*)&Lo[o] = *(const uint4*)lo;
}

// =====================================================================================
// packA_T: weight W [M=512][K] fp32 -> transposed packed [K/8][512][8] hi/lo
// grid: (K/64, 512/64)
// =====================================================================================
__global__ __launch_bounds__(256) void packA_T(const float* __restrict__ W,
    u16* __restrict__ Hi, u16* __restrict__ Lo, int Kdim)
{
    __shared__ float tile[64][65];
    const int t = threadIdx.x;
    const int k0 = blockIdx.x * 64, m0 = blockIdx.y * 64;
    const int kk = t & 63, mb = t >> 6;
    #pragma unroll
    for (int it = 0; it < 16; ++it) {
        int mm = mb + it * 4;
        tile[mm][kk] = W[(size_t)(m0 + mm) * Kdim + k0 + kk];
    }
    __syncthreads();
    #pragma unroll
    for (int cc = 0; cc < 2; ++cc) {
        int c = t + cc * 256;
        int kp = c >> 6, m = c & 63;
        u16 hi[8], lo[8];
        #pragma unroll
        for (int j = 0; j < 8; ++j) {
            float v = tile[m][kp * 8 + j];
            u16 h = f2h(v);
            hi[j] = h;
            lo[j] = f2h(v - h2f(h));
        }
        size_t o = ((size_t)(k0 / 8 + kp) * CH + m0 + m) * 8;
        *(uint4*)&Hi[o] = *(const uint4*)hi;
        *(uint4*)&Lo[o] = *(const uint4*)lo;
    }
}

// =====================================================================================
// pack_hvT: Hv fp32 [C][N] (batched) -> HvT packed [N/8][C][8] hi/lo and (Hv^2)T hi/lo
// grid: (N/64, C/64, 2=batch)
// =====================================================================================
__global__ __launch_bounds__(256) void pack_hvT(const float* __restrict__ Hv,
    u16* __restrict__ H1h, u16* __restrict__ H1l,
    u16* __restrict__ H2h, u16* __restrict__ H2l)
{
    __shared__ float tile[64][65];
    const int t = threadIdx.x;
    const int s0 = blockIdx.x * 64, c0 = blockIdx.y * 64;
    const int z = blockIdx.z;
    const float* src = Hv + (size_t)z * CH * NS;
    const int ss = t & 63, cb = t >> 6;
    #pragma unroll
    for (int it = 0; it < 16; ++it) {
        int cc = cb + it * 4;
        tile[cc][ss] = src[(size_t)(c0 + cc) * NS + s0 + ss];
    }
    __syncthreads();
    const size_t zb = (size_t)z * NS * CH;
    #pragma unroll
    for (int cc2 = 0; cc2 < 2; ++cc2) {
        int c = t + cc2 * 256;
        int sp = c >> 6, cm = c & 63;
        u16 h1[8], l1[8], h2[8], l2[8];
        #pragma unroll
        for (int j = 0; j < 8; ++j) {
            float v = tile[cm][sp * 8 + j];
            u16 a = f2h(v); h1[j] = a; l1[j] = f2h(v - h2f(a));
            float v2 = v * v;
            u16 b = f2h(v2); h2[j] = b; l2[j] = f2h(v2 - h2f(b));
        }
        size_t o = zb + ((size_t)(s0 / 8 + sp) * CH + c0 + cm) * 8;
        *(uint4*)&H1h[o] = *(const uint4*)h1;
        *(uint4*)&H1l[o] = *(const uint4*)l1;
        *(uint4*)&H2h[o] = *(const uint4*)h2;
        *(uint4*)&H2l[o] = *(const uint4*)l2;
    }
}

// =====================================================================================
// column softmax stats over S^T [s][n]: online max + sum(exp) per column n
// =====================================================================================
__global__ __launch_bounds__(256) void colstats_part(const float* __restrict__ S,
    float* __restrict__ pm, float* __restrict__ ps)
{
    const int n = blockIdx.x * 256 + threadIdx.x;
    const int s0 = blockIdx.y * 256;
    float m = -3.0e38f, sum = 0.f;
    for (int s = s0; s < s0 + 256; ++s) {
        float x = S[(size_t)s * NS + n];
        float nm = fmaxf(m, x);
        sum = sum * __expf(m - nm) + __expf(x - nm);
        m = nm;
    }
    pm[blockIdx.y * NS + n] = m;
    ps[blockIdx.y * NS + n] = sum;
}

__global__ __launch_bounds__(256) void colstats_comb(const float* __restrict__ pm,
    const float* __restrict__ ps, float* __restrict__ mx, float* __restrict__ inv)
{
    const int n = blockIdx.x * 256 + threadIdx.x;
    float m = -3.0e38f, s = 0.f;
    #pragma unroll
    for (int g = 0; g < 16; ++g) {
        float gm = pm[g * NS + n], gs = ps[g * NS + n];
        float nm = fmaxf(m, gm);
        s = s * __expf(m - nm) + gs * __expf(gm - nm);
        m = nm;
    }
    mx[n] = m;
    inv[n] = 1.f / s;
}

// ================= per-(b,c) content stats =================
__global__ __launch_bounds__(256) void content_stats(const float* __restrict__ content,
                                                     float* __restrict__ cmean,
                                                     float* __restrict__ cinv)
{
    const int bc = blockIdx.x;
    const float4* p = (const float4*)(content + (size_t)bc * NS);
    const int t = threadIdx.x;
    float s = 0.f, s2 = 0.f;
    #pragma unroll
    for (int j = 0; j < 4; ++j) {
        float4 v = p[t + j * 256];
        s  += (v.x + v.y) + (v.z + v.w);
        s2 += (v.x * v.x + v.y * v.y) + (v.z * v.z + v.w * v.w);
    }
    #pragma unroll
    for (int off = 32; off >= 1; off >>= 1) {
        s  += __shfl_xor(s, off);
        s2 += __shfl_xor(s2, off);
    }
    __shared__ float r1[4], r2[4];
    const int wid = t >> 6;
    if ((t & 63) == 0) { r1[wid] = s; r2[wid] = s2; }
    __syncthreads();
    if (t == 0) {
        s  = (r1[0] + r1[1]) + (r1[2] + r1[3]);
        s2 = (r2[0] + r2[1]) + (r2[2] + r2[3]);
        const float mean = s * (1.0f / 4096.f);
        const float var = (s2 - 4096.f * mean * mean) * (1.0f / 4095.f);
        cmean[bc] = mean;
        cinv[bc] = rsqrtf(fmaxf(var, 0.f) + EPSV);
    }
}

// ================= O = sqrt(max(E[x^2]-E[x]^2,0)) * norm(content) + E[x] =================
__global__ __launch_bounds__(256) void compute_O(const float* __restrict__ Mean,
                                                 const float* __restrict__ Sec,
                                                 const float* __restrict__ content,
                                                 const float* __restrict__ cmean,
                                                 const float* __restrict__ cinv,
                                                 float* __restrict__ O)
{
    const int idx = blockIdx.x * 256 + threadIdx.x;
    const int bc = idx >> 10;
    float4 mn = ((const float4*)Mean)[idx];
    float4 sc = ((const float4*)Sec)[idx];
    float4 ct = ((const float4*)content)[idx];
    const float cm = cmean[bc], ci = cinv[bc];
    float4 o;
    o.x = sqrtf(fmaxf(sc.x - mn.x * mn.x, 0.f)) * ((ct.x - cm) * ci) + mn.x;
    o.y = sqrtf(fmaxf(sc.y - mn.y * mn.y, 0.f)) * ((ct.y - cm) * ci) + mn.y;
    o.z = sqrtf(fmaxf(sc.z - mn.z * mn.z, 0.f)) * ((ct.z - cm) * ci) + mn.z;
    o.w = sqrtf(fmaxf(sc.w - mn.w * mn.w, 0.f)) * ((ct.w - cm) * ci) + mn.w;
    ((float4*)O)[idx] = o;
}

// =====================================================================================
extern "C" void kernel_launch(void* const* d_in, const int* in_sizes, int n_in,
                              void* d_out, int out_size, void* d_ws, size_t ws_size,
                              hipStream_t stream)
{
    const float* content = (const float*)d_in[0];
    const float* style   = (const float*)d_in[1];
    const float* f_w   = (const float*)d_in[2];
    const float* f_b   = (const float*)d_in[3];
    const float* g_w   = (const float*)d_in[4];
    const float* g_b   = (const float*)d_in[5];
    const float* h_w   = (const float*)d_in[6];
    const float* h_b   = (const float*)d_in[7];
    const float* out_w = (const float*)d_in[8];
    const float* out_b = (const float*)d_in[9];
    float* out = (float*)d_out;

    char* ws = (char*)d_ws;
    size_t off = 0;
    auto alloc = [&](size_t bytes) -> void* {
        void* p = ws + off;
        off = (off + bytes + 255) & ~(size_t)255;
        return p;
    };

    const size_t KN = (size_t)CH * NS;        // 2,097,152 elements (one batch plane)

    // ---- weight packs: 4 x (hi,lo) of 512x512 fp16 ----
    u16 *Wh[4], *Wl[4];
    for (int w = 0; w < 4; ++w) { Wh[w] = (u16*)alloc(CH * CH * 2); Wl[w] = (u16*)alloc(CH * CH * 2); }

    // ---- R2: one 8*KN u16 region. Two overlapping (time-disjoint) layouts:
    //   phase 1 (conv inputs):  [Xc_hi | Xc_lo | Xs_hi | Xs_lo]          (each 2KN)
    //   phase 2 (PV A-packs):   [HvT_hi | Hv2T_hi | HvT_lo | Hv2T_lo]    (each 2KN)
    //   phase-2 layout makes z-stride 2KN valid for BOTH hi and lo pointers.
    u16* R2 = (u16*)alloc(8 * KN * 2);
    u16* Xc_hi = R2;            u16* Xc_lo = R2 + 2 * KN;
    u16* Xs_hi = R2 + 4 * KN;   u16* Xs_lo = R2 + 6 * KN;
    u16* HvT_hi  = R2;              // z=0 A-hi
    u16* Hv2T_hi = R2 + 2 * KN;     // z=1 A-hi  (= HvT_hi + 2KN)
    u16* HvT_lo  = R2 + 4 * KN;     // z=0 A-lo
    u16* Hv2T_lo = R2 + 6 * KN;     // z=1 A-lo  (= HvT_lo + 2KN)

    // ---- R3: Fq/Gk packs; Gk pack reused as O pack ----
    u16* Fqp_hi = (u16*)alloc(2 * KN * 2);  u16* Fqp_lo = (u16*)alloc(2 * KN * 2);
    u16* Gkp_hi = (u16*)alloc(2 * KN * 2);  u16* Gkp_lo = (u16*)alloc(2 * KN * 2);
    u16* Op_hi = Gkp_hi;  u16* Op_lo = Gkp_lo;     // alias: Gk packs dead after last QK

    // ---- R4: P pack (hi only, one batch at a time) ----
    u16* Pp_hi = (u16*)alloc((size_t)NS * NS * 2);

    // ---- R5: fp32 union: {Fq32,Gk32,Hv32} -> S32 -> O32 (67.2 MB) ----
    char* R5 = (char*)alloc((size_t)NS * NS * 4);
    float* Fq32 = (float*)R5;
    float* Gk32 = (float*)(R5 + 2 * KN * 4);
    float* Hv32 = (float*)(R5 + 4 * KN * 4);
    float* S32  = (float*)R5;                      // after packs of Fq/Gk/Hv
    float* O32  = (float*)R5;                      // after last PV

    // ---- R6: Mean/Sec fp32 (contiguous so PV's z-stride covers Mean->Sec) ----
    float* Mean32 = (float*)alloc(2 * KN * 4);
    float* Sec32  = (float*)alloc(2 * KN * 4);

    // ---- small ----
    float* pm    = (float*)alloc(16 * NS * 4);
    float* ps    = (float*)alloc(16 * NS * 4);
    float* mxv   = (float*)alloc(NS * 4);
    float* invv  = (float*)alloc(NS * 4);
    float* cmean = (float*)alloc(1024 * 4);
    float* cinv  = (float*)alloc(1024 * 4);
    (void)ws_size; (void)in_sizes; (void)n_in; (void)out_size;

    // ================= pipeline =================
    // weight + input packs
    packA_T<<<dim3(8, 8), 256, 0, stream>>>(f_w,   Wh[0], Wl[0], CH);
    packA_T<<<dim3(8, 8), 256, 0, stream>>>(g_w,   Wh[1], Wl[1], CH);
    packA_T<<<dim3(8, 8), 256, 0, stream>>>(h_w,   Wh[2], Wl[2], CH);
    packA_T<<<dim3(8, 8), 256, 0, stream>>>(out_w, Wh[3], Wl[3], CH);
    packB_k<false, true><<<dim3(16, 64, 2), 256, 0, stream>>>(content, Xc_hi, Xc_lo, nullptr, nullptr, NS, (long)KN, (long)KN);
    packB_k<false, true><<<dim3(16, 64, 2), 256, 0, stream>>>(style,   Xs_hi, Xs_lo, nullptr, nullptr, NS, (long)KN, (long)KN);
    content_stats<<<1024, 256, 0, stream>>>(content, cmean, cinv);

    // convs (fp32 out, bias): 3-term split fp16
    gemm_split<4, true, false><<<dim3(32, 4, 2), 256, 0, stream>>>(
        Wh[0], Wl[0], Xc_hi, Xc_lo, f_b, nullptr, Fq32, CH, NS, CH, 0, (long)KN, (long)KN);
    gemm_split<4, true, false><<<dim3(32, 4, 2), 256, 0, stream>>>(
        Wh[1], Wl[1], Xs_hi, Xs_lo, g_b, nullptr, Gk32, CH, NS, CH, 0, (long)KN, (long)KN);
    gemm_split<4, true, false><<<dim3(32, 4, 2), 256, 0, stream>>>(
        Wh[2], Wl[2], Xs_hi, Xs_lo, h_b, nullptr, Hv32, CH, NS, CH, 0, (long)KN, (long)KN);

    // re-pack conv outputs for attention GEMMs
    packB_k<false, true><<<dim3(16, 64, 2), 256, 0, stream>>>(Fq32, Fqp_hi, Fqp_lo, nullptr, nullptr, NS, (long)KN, (long)KN);
    packB_k<false, true><<<dim3(16, 64, 2), 256, 0, stream>>>(Gk32, Gkp_hi, Gkp_lo, nullptr, nullptr, NS, (long)KN, (long)KN);
    // NOTE: overwrites R2 (Xc/Xs packs dead by now) with phase-2 layout
    pack_hvT<<<dim3(64, 8, 2), 256, 0, stream>>>(Hv32, HvT_hi, HvT_lo, Hv2T_hi, Hv2T_lo);

    for (int b = 0; b < 2; ++b) {
        const size_t bo = (size_t)b * KN;
        // QK^T: S^T[s][n] = sum_k Gk[k][s] * Fq[k][n]   (M = s = 4096), 3-term
        gemm_split<4, false, false><<<dim3(32, 32, 1), 256, 0, stream>>>(
            Gkp_hi + bo, Gkp_lo + bo, Fqp_hi + bo, Fqp_lo + bo, nullptr, nullptr,
            S32, NS, NS, CH, 0, 0, 0);
        // column softmax stats + fused exp/scale pack (P: fp16 hi only)
        colstats_part<<<dim3(16, 16), 256, 0, stream>>>(S32, pm, ps);
        colstats_comb<<<16, 256, 0, stream>>>(pm, ps, mxv, invv);
        packB_k<true, false><<<dim3(16, 512, 1), 256, 0, stream>>>(S32, Pp_hi, nullptr, mxv, invv, NS, 0, 0);
        // PV (2-term): z=0 -> Mean (A=HvT), z=1 -> Sec (A=Hv2T); B = P (hi only, shared
        // between Mean and Sec so its quantization error cancels in Var = Sec - Mean^2)
        gemm_split<3, false, false><<<dim3(32, 4, 2), 256, 0, stream>>>(
            HvT_hi + bo, HvT_lo + bo, Pp_hi, nullptr, nullptr, nullptr,
            Mean32 + bo, CH, NS, NS, (long)(2 * KN), 0, (long)(2 * KN));
    }

    compute_O<<<4096, 256, 0, stream>>>(Mean32, Sec32, content, cmean, cinv, O32);
    packB_k<false, true><<<dim3(16, 64, 2), 256, 0, stream>>>(O32, Op_hi, Op_lo, nullptr, nullptr, NS, (long)KN, (long)KN);
    // out conv: bias + residual(content) -> d_out
    gemm_split<4, true, true><<<dim3(32, 4, 2), 256, 0, stream>>>(
        Wh[3], Wl[3], Op_hi, Op_lo, out_b, content, out, CH, NS, CH, 0, (long)KN, (long)KN);
}

// Round 6
// 394.762 us; speedup vs baseline: 4.0899x; 1.2439x over previous
//
#include <hip/hip_runtime.h>
#include <math.h>

#define NS 4096
#define CH 512
#define EPSV 1e-5f

typedef __attribute__((ext_vector_type(8))) _Float16 f16x8;  // 8 x fp16 MFMA operand
typedef __attribute__((ext_vector_type(4))) float f32x4;     // MFMA accumulator
typedef unsigned short u16;

// ---------- fp16 helpers (RNE via cast) ----------
__device__ __forceinline__ u16 f2h(float x) {
    _Float16 h = (_Float16)x;
    return __builtin_bit_cast(unsigned short, h);
}
__device__ __forceinline__ float h2f(u16 b) {
    return (float)__builtin_bit_cast(_Float16, b);
}

// ---------- async global->LDS, 16B per lane ----------
__device__ __forceinline__ void gload16(const void* g, void* l) {
    __builtin_amdgcn_global_load_lds((const __attribute__((address_space(1))) unsigned*)g,
                                     (__attribute__((address_space(3))) unsigned*)l, 16, 0, 0);
}

// per-z dispatch table: offsets (elements) applied to A(hi,lo), B(hi,lo), out; output
// mode (0 = fp32, 1 = packed fp16 hi/lo in [K/8][N][8] layout); optional bias pointer.
struct ZTab {
    long aoff[6];
    long boff[6];
    long ooff[6];
    int  mode[6];
    const float* bias[6];
};

// =====================================================================================
// Split-fp16 GEMM:  out[m][n] = sum_k A[k][m] * B[k][n]  (+bias) (+resid)
//   NP=4: A = Ahi+Alo, B = Bhi+Blo; 3 MFMA terms (hh + hl + lh), ll ~2^-22 dropped.
//   NP=3: A = Ahi+Alo, B = Bhi only; 2 MFMA terms (PV: B=P shared by Mean/Sec ->
//         correlated quantization error cancels in Var = Sec - Mean^2).
// Packed operand layout: element (k, x) at ((k>>3)*W + x)*8 + (k&7)
// Tile 128x128, BK=32, 4 waves (2x2), per-wave 64x64 via 4x4 frags of 16x16x32.
// 2-phase double-buffered pipeline; epilogue can emit fp32 or packed fp16 hi/lo.
// =====================================================================================
template<int NP, bool RESID>
__global__ __launch_bounds__(256, (NP == 3 ? 3 : 2)) void gemm_split(
    const u16* __restrict__ Ahi, const u16* __restrict__ Alo,
    const u16* __restrict__ Bhi, const u16* __restrict__ Blo,
    const float* __restrict__ resid,
    float* __restrict__ outF, u16* __restrict__ outH, u16* __restrict__ outL,
    int Mw, int Nw, int K, ZTab tab)
{
    __shared__ u16 smem[2][NP * 4 * 128 * 8];   // 2 x (NP*8KB) double buffer
    const int t = threadIdx.x;
    const int lane = t & 63;
    const int wid = t >> 6;
    const int wm = wid >> 1, wn = wid & 1;
    const int lk = lane >> 4, lm = lane & 15;
    const int m0 = blockIdx.y * 128, n0 = blockIdx.x * 128;
    const int z = blockIdx.z;
    const u16* pAhi = Ahi + tab.aoff[z];
    const u16* pAlo = Alo + tab.aoff[z];
    const u16* pBhi = Bhi + tab.boff[z];
    const u16* pBlo = (NP == 4) ? (Blo + tab.boff[z]) : nullptr;

    f32x4 acc[4][4] = {};

    // stage K-tile ks into LDS buffer buf (2*NP x 16B chunks per thread)
    auto stage = [&](int buf, int ks) {
        const int kp0 = ks << 2;
        #pragma unroll
        for (int i = 0; i < 2 * NP; ++i) {
            const int q = i * 4 + wid;                 // wave-uniform
            const int b = q >> 3;                      // plane id
            const int p = (q & 7) >> 1;                // k-plane
            const int w = ((q & 1) << 6) + lane;       // width index 0..127
            const u16* src;
            if (b == 0)      src = pAhi + ((size_t)(kp0 + p) * Mw + m0 + w) * 8;
            else if (b == 1) src = pAlo + ((size_t)(kp0 + p) * Mw + m0 + w) * 8;
            else if (b == 2) src = pBhi + ((size_t)(kp0 + p) * Nw + n0 + w) * 8;
            else             src = pBlo + ((size_t)(kp0 + p) * Nw + n0 + w) * 8;
            gload16(src, &smem[buf][(size_t)(((b * 4 + p) * 128) + w) * 8]);
        }
    };

    const int nK = K >> 5;
    stage(0, 0);
    __syncthreads();                 // drains vmcnt(0): buf0 ready
    int cur = 0;
    for (int ks = 0; ks < nK; ++ks) {
        if (ks + 1 < nK) stage(cur ^ 1, ks + 1);   // prefetch next tile during MFMA
        const u16* sm = smem[cur];
        f16x8 ah[4], al[4], bh[4], bl[4];
        #pragma unroll
        for (int f = 0; f < 4; ++f) {
            ah[f] = *(const f16x8*)&sm[((0 * 4 + lk) * 128 + wm * 64 + f * 16 + lm) * 8];
            al[f] = *(const f16x8*)&sm[((1 * 4 + lk) * 128 + wm * 64 + f * 16 + lm) * 8];
            bh[f] = *(const f16x8*)&sm[((2 * 4 + lk) * 128 + wn * 64 + f * 16 + lm) * 8];
            if (NP == 4)
                bl[f] = *(const f16x8*)&sm[((3 * 4 + lk) * 128 + wn * 64 + f * 16 + lm) * 8];
        }
        #pragma unroll
        for (int i = 0; i < 4; ++i)
            #pragma unroll
            for (int j = 0; j < 4; ++j) {
                acc[i][j] = __builtin_amdgcn_mfma_f32_16x16x32_f16(ah[i], bh[j], acc[i][j], 0, 0, 0);
                if (NP == 4)
                    acc[i][j] = __builtin_amdgcn_mfma_f32_16x16x32_f16(ah[i], bl[j], acc[i][j], 0, 0, 0);
                acc[i][j] = __builtin_amdgcn_mfma_f32_16x16x32_f16(al[i], bh[j], acc[i][j], 0, 0, 0);
            }
        __syncthreads();             // prefetched buffer complete, reads done
        cur ^= 1;
    }
    // ---- epilogue: C/D layout col = lane&15, row = (lane>>4)*4 + reg ----
    const float* bp = tab.bias[z];
    if (tab.mode[z] == 0) {
        float* pout = outF + tab.ooff[z];
        #pragma unroll
        for (int i = 0; i < 4; ++i) {
            #pragma unroll
            for (int r = 0; r < 4; ++r) {
                const int m = m0 + wm * 64 + i * 16 + lk * 4 + r;
                const float bv = bp ? bp[m] : 0.f;
                const size_t ro = (size_t)m * Nw + n0 + wn * 64 + lm;
                #pragma unroll
                for (int j = 0; j < 4; ++j) {
                    float v = acc[i][j][r] + bv;
                    if (RESID) v += resid[tab.ooff[z] + ro + j * 16];
                    pout[ro + j * 16] = v;
                }
            }
        }
    } else {
        // packed fp16 hi/lo out: element (k=m, x=n) -> ((m>>3)*Nw + n)*8 + (m&7)
        u16* ph = outH + tab.ooff[z];
        u16* pl = outL + tab.ooff[z];
        #pragma unroll
        for (int i = 0; i < 4; ++i) {
            float bv[4];
            #pragma unroll
            for (int r = 0; r < 4; ++r) {
                const int m = m0 + wm * 64 + i * 16 + lk * 4 + r;
                bv[r] = bp ? bp[m] : 0.f;
            }
            const long rg = (long)((m0 + wm * 64) >> 3) + i * 2 + (lk >> 1);
            const int sub = (lk & 1) * 4;
            #pragma unroll
            for (int j = 0; j < 4; ++j) {
                const int n = n0 + wn * 64 + j * 16 + lm;
                const long idx = (rg * Nw + n) * 8 + sub;
                u16 h[4], l[4];
                #pragma unroll
                for (int r = 0; r < 4; ++r) {
                    float v = acc[i][j][r] + bv[r];
                    h[r] = f2h(v);
                    l[r] = f2h(v - h2f(h[r]));
                }
                *(ushort4*)&ph[idx] = make_ushort4(h[0], h[1], h[2], h[3]);
                *(ushort4*)&pl[idx] = make_ushort4(l[0], l[1], l[2], l[3]);
            }
        }
    }
}

// =====================================================================================
// packB: fp32 [K][N] (batched) -> fp16 hi(/lo) packed [K/8][N][8]. Optional fused exp.
// grid: (N/256, K/8, batches)
// =====================================================================================
template<bool EXPSC, bool WLO>
__global__ __launch_bounds__(256) void packB_k(const float* __restrict__ X,
    u16* __restrict__ Hi, u16* __restrict__ Lo,
    const float* __restrict__ mx, const float* __restrict__ inv,
    int Nw, long xB, long pB)
{
    const int n = blockIdx.x * 256 + threadIdx.x;
    const int p = blockIdx.y;
    const int z = blockIdx.z;
    const float* Xp = X + (size_t)z * xB + ((size_t)p * 8) * Nw + n;
    float em = 0.f, ei = 1.f;
    if (EXPSC) { em = mx[n]; ei = inv[n]; }
    u16 hi[8], lo[8];
    #pragma unroll
    for (int j = 0; j < 8; ++j) {
        float v = Xp[(size_t)j * Nw];
        if (EXPSC) v = __expf(v - em) * ei;
        u16 h = f2h(v);
        hi[j] = h;
        if (WLO) lo[j] = f2h(v - h2f(h));
    }
    const size_t o = (size_t)z * pB + ((size_t)p * Nw + n) * 8;
    *(uint4*)&Hi[o] = *(const uint4*)hi;
    if (WLO) *(uint4*)&Lo[o] = *(const uint4*)lo;
}

// =====================================================================================
// packA_T: weight W [M=512][K] fp32 -> transposed packed [K/8][512][8] hi/lo
// grid: (K/64, 512/64)
// =====================================================================================
__global__ __launch_bounds__(256) void packA_T(const float* __restrict__ W,
    u16* __restrict__ Hi, u16* __restrict__ Lo, int Kdim)
{
    __shared__ float tile[64][65];
    const int t = threadIdx.x;
    const int k0 = blockIdx.x * 64, m0 = blockIdx.y * 64;
    const int kk = t & 63, mb = t >> 6;
    #pragma unroll
    for (int it = 0; it < 16; ++it) {
        int mm = mb + it * 4;
        tile[mm][kk] = W[(size_t)(m0 + mm) * Kdim + k0 + kk];
    }
    __syncthreads();
    #pragma unroll
    for (int cc = 0; cc < 2; ++cc) {
        int c = t + cc * 256;
        int kp = c >> 6, m = c & 63;
        u16 hi[8], lo[8];
        #pragma unroll
        for (int j = 0; j < 8; ++j) {
            float v = tile[m][kp * 8 + j];
            u16 h = f2h(v);
            hi[j] = h;
            lo[j] = f2h(v - h2f(h));
        }
        size_t o = ((size_t)(k0 / 8 + kp) * CH + m0 + m) * 8;
        *(uint4*)&Hi[o] = *(const uint4*)hi;
        *(uint4*)&Lo[o] = *(const uint4*)lo;
    }
}

// =====================================================================================
// pack_hvT: Hv fp32 [C][N] (batched) -> HvT packed [N/8][C][8] hi/lo and (Hv^2)T hi/lo
// grid: (N/64, C/64, 2=batch)
// =====================================================================================
__global__ __launch_bounds__(256) void pack_hvT(const float* __restrict__ Hv,
    u16* __restrict__ H1h, u16* __restrict__ H1l,
    u16* __restrict__ H2h, u16* __restrict__ H2l)
{
    __shared__ float tile[64][65];
    const int t = threadIdx.x;
    const int s0 = blockIdx.x * 64, c0 = blockIdx.y * 64;
    const int z = blockIdx.z;
    const float* src = Hv + (size_t)z * CH * NS;
    const int ss = t & 63, cb = t >> 6;
    #pragma unroll
    for (int it = 0; it < 16; ++it) {
        int cc = cb + it * 4;
        tile[cc][ss] = src[(size_t)(c0 + cc) * NS + s0 + ss];
    }
    __syncthreads();
    const size_t zb = (size_t)z * NS * CH;
    #pragma unroll
    for (int cc2 = 0; cc2 < 2; ++cc2) {
        int c = t + cc2 * 256;
        int sp = c >> 6, cm = c & 63;
        u16 h1[8], l1[8], h2[8], l2[8];
        #pragma unroll
        for (int j = 0; j < 8; ++j) {
            float v = tile[cm][sp * 8 + j];
            u16 a = f2h(v); h1[j] = a; l1[j] = f2h(v - h2f(a));
            float v2 = v * v;
            u16 b = f2h(v2); h2[j] = b; l2[j] = f2h(v2 - h2f(b));
        }
        size_t o = zb + ((size_t)(s0 / 8 + sp) * CH + c0 + cm) * 8;
        *(uint4*)&H1h[o] = *(const uint4*)h1;
        *(uint4*)&H1l[o] = *(const uint4*)l1;
        *(uint4*)&H2h[o] = *(const uint4*)h2;
        *(uint4*)&H2l[o] = *(const uint4*)l2;
    }
}

// =====================================================================================
// column softmax stats over S^T [s][n]: online max + sum(exp) per column n
// =====================================================================================
__global__ __launch_bounds__(256) void colstats_part(const float* __restrict__ S,
    float* __restrict__ pm, float* __restrict__ ps)
{
    const int n = blockIdx.x * 256 + threadIdx.x;
    const int s0 = blockIdx.y * 256;
    float m = -3.0e38f, sum = 0.f;
    for (int s = s0; s < s0 + 256; ++s) {
        float x = S[(size_t)s * NS + n];
        float nm = fmaxf(m, x);
        sum = sum * __expf(m - nm) + __expf(x - nm);
        m = nm;
    }
    pm[blockIdx.y * NS + n] = m;
    ps[blockIdx.y * NS + n] = sum;
}

__global__ __launch_bounds__(256) void colstats_comb(const float* __restrict__ pm,
    const float* __restrict__ ps, float* __restrict__ mx, float* __restrict__ inv)
{
    const int n = blockIdx.x * 256 + threadIdx.x;
    float m = -3.0e38f, s = 0.f;
    #pragma unroll
    for (int g = 0; g < 16; ++g) {
        float gm = pm[g * NS + n], gs = ps[g * NS + n];
        float nm = fmaxf(m, gm);
        s = s * __expf(m - nm) + gs * __expf(gm - nm);
        m = nm;
    }
    mx[n] = m;
    inv[n] = 1.f / s;
}

// ================= per-(b,c) content stats =================
__global__ __launch_bounds__(256) void content_stats(const float* __restrict__ content,
                                                     float* __restrict__ cmean,
                                                     float* __restrict__ cinv)
{
    const int bc = blockIdx.x;
    const float4* p = (const float4*)(content + (size_t)bc * NS);
    const int t = threadIdx.x;
    float s = 0.f, s2 = 0.f;
    #pragma unroll
    for (int j = 0; j < 4; ++j) {
        float4 v = p[t + j * 256];
        s  += (v.x + v.y) + (v.z + v.w);
        s2 += (v.x * v.x + v.y * v.y) + (v.z * v.z + v.w * v.w);
    }
    #pragma unroll
    for (int off = 32; off >= 1; off >>= 1) {
        s  += __shfl_xor(s, off);
        s2 += __shfl_xor(s2, off);
    }
    __shared__ float r1[4], r2[4];
    const int wid = t >> 6;
    if ((t & 63) == 0) { r1[wid] = s; r2[wid] = s2; }
    __syncthreads();
    if (t == 0) {
        s  = (r1[0] + r1[1]) + (r1[2] + r1[3]);
        s2 = (r2[0] + r2[1]) + (r2[2] + r2[3]);
        const float mean = s * (1.0f / 4096.f);
        const float var = (s2 - 4096.f * mean * mean) * (1.0f / 4095.f);
        cmean[bc] = mean;
        cinv[bc] = rsqrtf(fmaxf(var, 0.f) + EPSV);
    }
}

// ================= O = sqrt(max(E[x^2]-E[x]^2,0)) * norm(content) + E[x] =================
__global__ __launch_bounds__(256) void compute_O(const float* __restrict__ Mean,
                                                 const float* __restrict__ Sec,
                                                 const float* __restrict__ content,
                                                 const float* __restrict__ cmean,
                                                 const float* __restrict__ cinv,
                                                 float* __restrict__ O)
{
    const int idx = blockIdx.x * 256 + threadIdx.x;
    const int bc = idx >> 10;
    float4 mn = ((const float4*)Mean)[idx];
    float4 sc = ((const float4*)Sec)[idx];
    float4 ct = ((const float4*)content)[idx];
    const float cm = cmean[bc], ci = cinv[bc];
    float4 o;
    o.x = sqrtf(fmaxf(sc.x - mn.x * mn.x, 0.f)) * ((ct.x - cm) * ci) + mn.x;
    o.y = sqrtf(fmaxf(sc.y - mn.y * mn.y, 0.f)) * ((ct.y - cm) * ci) + mn.y;
    o.z = sqrtf(fmaxf(sc.z - mn.z * mn.z, 0.f)) * ((ct.z - cm) * ci) + mn.z;
    o.w = sqrtf(fmaxf(sc.w - mn.w * mn.w, 0.f)) * ((ct.w - cm) * ci) + mn.w;
    ((float4*)O)[idx] = o;
}

// =====================================================================================
extern "C" void kernel_launch(void* const* d_in, const int* in_sizes, int n_in,
                              void* d_out, int out_size, void* d_ws, size_t ws_size,
                              hipStream_t stream)
{
    const float* content = (const float*)d_in[0];
    const float* style   = (const float*)d_in[1];
    const float* f_w   = (const float*)d_in[2];
    const float* f_b   = (const float*)d_in[3];
    const float* g_w   = (const float*)d_in[4];
    const float* g_b   = (const float*)d_in[5];
    const float* h_w   = (const float*)d_in[6];
    const float* h_b   = (const float*)d_in[7];
    const float* out_w = (const float*)d_in[8];
    const float* out_b = (const float*)d_in[9];
    float* out = (float*)d_out;

    char* ws = (char*)d_ws;
    size_t off = 0;
    auto alloc = [&](size_t bytes) -> void* {
        void* p = ws + off;
        off = (off + bytes + 255) & ~(size_t)255;
        return p;
    };

    const size_t KN   = (size_t)CH * NS;      // 2,097,152 elements (one batch plane)
    const size_t CHCH = (size_t)CH * CH;
    const long   NSNS = (long)NS * NS;

    // ---- weight packs: contiguous [Wh0 Wl0 Wh1 Wl1 Wh2 Wl2 Wh3 Wl3], each CHCH u16 ----
    u16 *Wh[4], *Wl[4];
    for (int w = 0; w < 4; ++w) { Wh[w] = (u16*)alloc(CHCH * 2); Wl[w] = (u16*)alloc(CHCH * 2); }

    // ---- R2: one 8*KN u16 region, two time-disjoint layouts:
    //   phase 1 (conv inputs):  [Xc_hi | Xc_lo | Xs_hi | Xs_lo]          (each 2KN)
    //   phase 2 (PV A-packs):   [HvT_hi | Hv2T_hi | HvT_lo | Hv2T_lo]    (each 2KN)
    u16* R2 = (u16*)alloc(8 * KN * 2);
    u16* Xc_hi = R2;            u16* Xc_lo = R2 + 2 * KN;
    u16* Xs_hi = R2 + 4 * KN;   u16* Xs_lo = R2 + 6 * KN;
    u16* HvT_hi  = R2;
    u16* Hv2T_hi = R2 + 2 * KN;
    u16* HvT_lo  = R2 + 4 * KN;
    u16* Hv2T_lo = R2 + 6 * KN;

    // ---- R3: contiguous [Fqp_hi | Fqp_lo | Gkp_hi | Gkp_lo], each 2KN u16;
    //          Gk packs reused as O packs after last QK ----
    u16* Fqp_hi = (u16*)alloc(2 * KN * 2);  u16* Fqp_lo = (u16*)alloc(2 * KN * 2);
    u16* Gkp_hi = (u16*)alloc(2 * KN * 2);  u16* Gkp_lo = (u16*)alloc(2 * KN * 2);
    u16* Op_hi = Gkp_hi;  u16* Op_lo = Gkp_lo;

    // ---- R4: P packs (hi only), BOTH batches for merged PV ----
    u16* Pp = (u16*)alloc(2 * (size_t)NS * NS * 2);

    // ---- R5: fp32 union: Hv32 -> S32 -> O32 (67.2 MB) ----
    char* R5 = (char*)alloc((size_t)NS * NS * 4);
    float* Hv32 = (float*)(R5 + 4 * KN * 4);   // conv z=4,5 output (dead after pack_hvT)
    float* S32  = (float*)R5;
    float* O32  = (float*)R5;

    // ---- R6: Mean/Sec fp32, contiguous (Sec32 = Mean32 + 2KN floats) ----
    float* Mean32 = (float*)alloc(2 * KN * 4);
    float* Sec32  = (float*)alloc(2 * KN * 4);

    // ---- small ----
    float* pm    = (float*)alloc(16 * NS * 4);
    float* ps    = (float*)alloc(16 * NS * 4);
    float* mxv   = (float*)alloc(NS * 4);
    float* invv  = (float*)alloc(NS * 4);
    float* cmean = (float*)alloc(1024 * 4);
    float* cinv  = (float*)alloc(1024 * 4);
    (void)ws_size; (void)in_sizes; (void)n_in; (void)out_size;

    // ================= pipeline =================
    packA_T<<<dim3(8, 8), 256, 0, stream>>>(f_w,   Wh[0], Wl[0], CH);
    packA_T<<<dim3(8, 8), 256, 0, stream>>>(g_w,   Wh[1], Wl[1], CH);
    packA_T<<<dim3(8, 8), 256, 0, stream>>>(h_w,   Wh[2], Wl[2], CH);
    packA_T<<<dim3(8, 8), 256, 0, stream>>>(out_w, Wh[3], Wl[3], CH);
    packB_k<false, true><<<dim3(16, 64, 2), 256, 0, stream>>>(content, Xc_hi, Xc_lo, nullptr, nullptr, NS, (long)KN, (long)KN);
    packB_k<false, true><<<dim3(16, 64, 2), 256, 0, stream>>>(style,   Xs_hi, Xs_lo, nullptr, nullptr, NS, (long)KN, (long)KN);
    content_stats<<<1024, 256, 0, stream>>>(content, cmean, cinv);

    // ---- merged conv3: z = w*2 + b; w=0 (f,content)->Fqp packed, w=1 (g,style)->Gkp
    //      packed, w=2 (h,style)->Hv32 fp32 ----
    {
        ZTab tb = {};
        const float* bs[3] = { f_b, g_b, h_b };
        for (int z = 0; z < 6; ++z) {
            const int w = z >> 1, b = z & 1;
            tb.aoff[z] = (long)(2 * w) * CHCH;
            tb.boff[z] = (w == 0 ? 0 : (long)(4 * KN)) + (long)b * KN;
            tb.mode[z] = (w < 2) ? 1 : 0;
            tb.ooff[z] = (w < 2) ? ((long)w * 4 * KN + (long)b * KN)   // u16 elems from Fqp bases
                                 : ((long)4 * KN + (long)b * KN);      // fp32 elems from R5 base
            tb.bias[z] = bs[w];
        }
        gemm_split<4, false><<<dim3(32, 4, 6), 256, 0, stream>>>(
            Wh[0], Wh[0] + CHCH, Xc_hi, Xc_hi + 2 * KN, nullptr,
            (float*)R5, Fqp_hi, Fqp_hi + 2 * KN, CH, NS, CH, tb);
    }

    // transposed Hv / Hv^2 packs (overwrites R2 phase-1; Xc/Xs dead)
    pack_hvT<<<dim3(64, 8, 2), 256, 0, stream>>>(Hv32, HvT_hi, HvT_lo, Hv2T_hi, Hv2T_lo);

    for (int b = 0; b < 2; ++b) {
        const long bo = (long)b * KN;
        // QK^T: S^T[s][n] = sum_k Gk[k][s] * Fq[k][n]
        ZTab tq = {};
        gemm_split<4, false><<<dim3(32, 32, 1), 256, 0, stream>>>(
            Gkp_hi + bo, Gkp_lo + bo, Fqp_hi + bo, Fqp_lo + bo, nullptr,
            S32, nullptr, nullptr, NS, NS, CH, tq);
        colstats_part<<<dim3(16, 16), 256, 0, stream>>>(S32, pm, ps);
        colstats_comb<<<16, 256, 0, stream>>>(pm, ps, mxv, invv);
        packB_k<true, false><<<dim3(16, 512, 1), 256, 0, stream>>>(
            S32, Pp + (size_t)b * NSNS, nullptr, mxv, invv, NS, 0, 0);
    }

    // ---- merged PV: z = b*2 + which; which=0 -> Mean (A=HvT), 1 -> Sec (A=Hv2T) ----
    {
        ZTab tp = {};
        for (int z = 0; z < 4; ++z) {
            const int b = z >> 1, which = z & 1;
            tp.aoff[z] = (long)which * 2 * KN + (long)b * KN;
            tp.boff[z] = (long)b * NSNS;
            tp.ooff[z] = (long)which * 2 * KN + (long)b * KN;
        }
        gemm_split<3, false><<<dim3(32, 4, 4), 256, 0, stream>>>(
            HvT_hi, HvT_lo, Pp, nullptr, nullptr,
            Mean32, nullptr, nullptr, CH, NS, NS, tp);
    }

    compute_O<<<4096, 256, 0, stream>>>(Mean32, Sec32, content, cmean, cinv, O32);
    packB_k<false, true><<<dim3(16, 64, 2), 256, 0, stream>>>(O32, Op_hi, Op_lo, nullptr, nullptr, NS, (long)KN, (long)KN);

    // ---- out conv: bias + residual(content) -> d_out ----
    {
        ZTab tf = {};
        for (int z = 0; z < 2; ++z) {
            tf.ooff[z] = (long)z * KN;
            tf.boff[z] = (long)z * KN;
            tf.bias[z] = out_b;
        }
        gemm_split<4, true><<<dim3(32, 4, 2), 256, 0, stream>>>(
            Wh[3], Wl[3], Op_hi, Op_lo, content,
            out, nullptr, nullptr, CH, NS, CH, tf);
    }
}

// Round 7
// 345.119 us; speedup vs baseline: 4.6783x; 1.1438x over previous
//
#include <hip/hip_runtime.h>
#include <math.h>

#define NS 4096
#define CH 512
#define EPSV 1e-5f

typedef __attribute__((ext_vector_type(8))) _Float16 f16x8;  // 8 x fp16 MFMA operand
typedef __attribute__((ext_vector_type(4))) float f32x4;     // MFMA accumulator
typedef unsigned short u16;

// ---------- fp16 helpers (RNE via cast) ----------
__device__ __forceinline__ u16 f2h(float x) {
    _Float16 h = (_Float16)x;
    return __builtin_bit_cast(unsigned short, h);
}
__device__ __forceinline__ float h2f(u16 b) {
    return (float)__builtin_bit_cast(_Float16, b);
}

// ---------- async global->LDS, 16B per lane ----------
__device__ __forceinline__ void gload16(const void* g, void* l) {
    __builtin_amdgcn_global_load_lds((const __attribute__((address_space(1))) unsigned*)g,
                                     (__attribute__((address_space(3))) unsigned*)l, 16, 0, 0);
}

// per-z dispatch table: offsets (elements) applied to A(hi,lo), B(hi,lo), out; output
// mode (0 = fp32, 1 = packed fp16 hi/lo in [K/8][N][8] layout); optional bias pointer.
struct ZTab {
    long aoff[6];
    long boff[6];
    long ooff[6];
    int  mode[6];
    const float* bias[6];
};

// =====================================================================================
// Split-fp16 GEMM:  out[m][n] = sum_k A[k][m] * B[k][n]  (+bias) (+resid)
//   NP=4: A = Ahi+Alo, B = Bhi+Blo; 3 MFMA terms (hh + hl + lh), ll ~2^-22 dropped.
//   NP=3: A = Ahi+Alo, B = Bhi only; 2 MFMA terms.
//     - PV: B = P shared by Mean/Sec -> correlated quantization error cancels in Var.
//     - QK: B = Fq hi-only; dropped G*Fq_lo term ~0.0055 logit sigma, perturbs the
//       SAME P used by Mean and Sec -> also correlated-safe.
// COLST: epilogue additionally emits per-column (n) partial softmax stats (max and
//   sum(exp(x-max))) over each 64-row group of this block's 128 s-rows.
// Packed operand layout: element (k, x) at ((k>>3)*W + x)*8 + (k&7)
// Tile 128x128, BK=32, 4 waves (2x2), per-wave 64x64 via 4x4 frags of 16x16x32.
// 2-phase double-buffered pipeline.
// =====================================================================================
template<int NP, bool RESID, bool COLST>
__global__ __launch_bounds__(256, (NP == 3 ? 3 : 2)) void gemm_split(
    const u16* __restrict__ Ahi, const u16* __restrict__ Alo,
    const u16* __restrict__ Bhi, const u16* __restrict__ Blo,
    const float* __restrict__ resid,
    float* __restrict__ outF, u16* __restrict__ outH, u16* __restrict__ outL,
    float* __restrict__ pmg, float* __restrict__ psg,
    int Mw, int Nw, int K, ZTab tab)
{
    __shared__ u16 smem[2][NP * 4 * 128 * 8];   // 2 x (NP*8KB) double buffer
    const int t = threadIdx.x;
    const int lane = t & 63;
    const int wid = t >> 6;
    const int wm = wid >> 1, wn = wid & 1;
    const int lk = lane >> 4, lm = lane & 15;
    const int m0 = blockIdx.y * 128, n0 = blockIdx.x * 128;
    const int z = blockIdx.z;
    const u16* pAhi = Ahi + tab.aoff[z];
    const u16* pAlo = Alo + tab.aoff[z];
    const u16* pBhi = Bhi + tab.boff[z];
    const u16* pBlo = (NP == 4) ? (Blo + tab.boff[z]) : nullptr;

    f32x4 acc[4][4] = {};

    // stage K-tile ks into LDS buffer buf (2*NP x 16B chunks per thread)
    auto stage = [&](int buf, int ks) {
        const int kp0 = ks << 2;
        #pragma unroll
        for (int i = 0; i < 2 * NP; ++i) {
            const int q = i * 4 + wid;                 // wave-uniform
            const int b = q >> 3;                      // plane id
            const int p = (q & 7) >> 1;                // k-plane
            const int w = ((q & 1) << 6) + lane;       // width index 0..127
            const u16* src;
            if (b == 0)      src = pAhi + ((size_t)(kp0 + p) * Mw + m0 + w) * 8;
            else if (b == 1) src = pAlo + ((size_t)(kp0 + p) * Mw + m0 + w) * 8;
            else if (b == 2) src = pBhi + ((size_t)(kp0 + p) * Nw + n0 + w) * 8;
            else             src = pBlo + ((size_t)(kp0 + p) * Nw + n0 + w) * 8;
            gload16(src, &smem[buf][(size_t)(((b * 4 + p) * 128) + w) * 8]);
        }
    };

    const int nK = K >> 5;
    stage(0, 0);
    __syncthreads();                 // drains vmcnt(0): buf0 ready
    int cur = 0;
    for (int ks = 0; ks < nK; ++ks) {
        if (ks + 1 < nK) stage(cur ^ 1, ks + 1);   // prefetch next tile during MFMA
        const u16* sm = smem[cur];
        f16x8 ah[4], al[4], bh[4], bl[4];
        #pragma unroll
        for (int f = 0; f < 4; ++f) {
            ah[f] = *(const f16x8*)&sm[((0 * 4 + lk) * 128 + wm * 64 + f * 16 + lm) * 8];
            al[f] = *(const f16x8*)&sm[((1 * 4 + lk) * 128 + wm * 64 + f * 16 + lm) * 8];
            bh[f] = *(const f16x8*)&sm[((2 * 4 + lk) * 128 + wn * 64 + f * 16 + lm) * 8];
            if (NP == 4)
                bl[f] = *(const f16x8*)&sm[((3 * 4 + lk) * 128 + wn * 64 + f * 16 + lm) * 8];
        }
        #pragma unroll
        for (int i = 0; i < 4; ++i)
            #pragma unroll
            for (int j = 0; j < 4; ++j) {
                acc[i][j] = __builtin_amdgcn_mfma_f32_16x16x32_f16(ah[i], bh[j], acc[i][j], 0, 0, 0);
                if (NP == 4)
                    acc[i][j] = __builtin_amdgcn_mfma_f32_16x16x32_f16(ah[i], bl[j], acc[i][j], 0, 0, 0);
                acc[i][j] = __builtin_amdgcn_mfma_f32_16x16x32_f16(al[i], bh[j], acc[i][j], 0, 0, 0);
            }
        __syncthreads();             // prefetched buffer complete, reads done
        cur ^= 1;
    }
    // ---- epilogue: C/D layout col = lane&15, row = (lane>>4)*4 + reg ----
    const float* bp = tab.bias[z];
    if (tab.mode[z] == 0) {
        float* pout = outF + tab.ooff[z];
        #pragma unroll
        for (int i = 0; i < 4; ++i) {
            #pragma unroll
            for (int r = 0; r < 4; ++r) {
                const int m = m0 + wm * 64 + i * 16 + lk * 4 + r;
                const float bv = bp ? bp[m] : 0.f;
                const size_t ro = (size_t)m * Nw + n0 + wn * 64 + lm;
                #pragma unroll
                for (int j = 0; j < 4; ++j) {
                    float v = acc[i][j][r] + bv;
                    if (RESID) v += resid[tab.ooff[z] + ro + j * 16];
                    pout[ro + j * 16] = v;
                }
            }
        }
    } else {
        // packed fp16 hi/lo out: element (k=m, x=n) -> ((m>>3)*Nw + n)*8 + (m&7)
        u16* ph = outH + tab.ooff[z];
        u16* pl = outL + tab.ooff[z];
        #pragma unroll
        for (int i = 0; i < 4; ++i) {
            float bv[4];
            #pragma unroll
            for (int r = 0; r < 4; ++r) {
                const int m = m0 + wm * 64 + i * 16 + lk * 4 + r;
                bv[r] = bp ? bp[m] : 0.f;
            }
            const long rg = (long)((m0 + wm * 64) >> 3) + i * 2 + (lk >> 1);
            const int sub = (lk & 1) * 4;
            #pragma unroll
            for (int j = 0; j < 4; ++j) {
                const int n = n0 + wn * 64 + j * 16 + lm;
                const long idx = (rg * Nw + n) * 8 + sub;
                u16 h[4], l[4];
                #pragma unroll
                for (int r = 0; r < 4; ++r) {
                    float v = acc[i][j][r] + bv[r];
                    h[r] = f2h(v);
                    l[r] = f2h(v - h2f(h[r]));
                }
                *(ushort4*)&ph[idx] = make_ushort4(h[0], h[1], h[2], h[3]);
                *(ushort4*)&pl[idx] = make_ushort4(l[0], l[1], l[2], l[3]);
            }
        }
    }
    if (COLST) {
        // per-column partial softmax stats over this wave-row's 64 s-rows.
        // column n = n0 + wn*64 + j*16 + lm is held by the 4 lanes lk=0..3 (16 acc each).
        #pragma unroll
        for (int j = 0; j < 4; ++j) {
            float mx = -3.0e38f;
            #pragma unroll
            for (int i = 0; i < 4; ++i)
                #pragma unroll
                for (int r = 0; r < 4; ++r)
                    mx = fmaxf(mx, acc[i][j][r]);
            mx = fmaxf(mx, __shfl_xor(mx, 16));
            mx = fmaxf(mx, __shfl_xor(mx, 32));
            float sum = 0.f;
            #pragma unroll
            for (int i = 0; i < 4; ++i)
                #pragma unroll
                for (int r = 0; r < 4; ++r)
                    sum += __expf(acc[i][j][r] - mx);
            sum += __shfl_xor(sum, 16);
            sum += __shfl_xor(sum, 32);
            if (lk == 0) {
                const int n = n0 + wn * 64 + j * 16 + lm;
                const int grp = (m0 >> 6) + wm;          // 64 row-groups
                pmg[(size_t)grp * NS + n] = mx;
                psg[(size_t)grp * NS + n] = sum;
            }
        }
    }
}

// =====================================================================================
// packB: fp32 [K][N] (batched) -> fp16 hi(/lo) packed [K/8][N][8]. Optional fused exp.
// grid: (N/256, K/8, batches)
// =====================================================================================
template<bool EXPSC, bool WLO>
__global__ __launch_bounds__(256) void packB_k(const float* __restrict__ X,
    u16* __restrict__ Hi, u16* __restrict__ Lo,
    const float* __restrict__ mx, const float* __restrict__ inv,
    int Nw, long xB, long pB)
{
    const int n = blockIdx.x * 256 + threadIdx.x;
    const int p = blockIdx.y;
    const int z = blockIdx.z;
    const float* Xp = X + (size_t)z * xB + ((size_t)p * 8) * Nw + n;
    float em = 0.f, ei = 1.f;
    if (EXPSC) { em = mx[n]; ei = inv[n]; }
    u16 hi[8], lo[8];
    #pragma unroll
    for (int j = 0; j < 8; ++j) {
        float v = Xp[(size_t)j * Nw];
        if (EXPSC) v = __expf(v - em) * ei;
        u16 h = f2h(v);
        hi[j] = h;
        if (WLO) lo[j] = f2h(v - h2f(h));
    }
    const size_t o = (size_t)z * pB + ((size_t)p * Nw + n) * 8;
    *(uint4*)&Hi[o] = *(const uint4*)hi;
    if (WLO) *(uint4*)&Lo[o] = *(const uint4*)lo;
}

// =====================================================================================
// packA_T: weight W [M=512][K] fp32 -> transposed packed [K/8][512][8] hi/lo
// grid: (K/64, 512/64)
// =====================================================================================
__global__ __launch_bounds__(256) void packA_T(const float* __restrict__ W,
    u16* __restrict__ Hi, u16* __restrict__ Lo, int Kdim)
{
    __shared__ float tile[64][65];
    const int t = threadIdx.x;
    const int k0 = blockIdx.x * 64, m0 = blockIdx.y * 64;
    const int kk = t & 63, mb = t >> 6;
    #pragma unroll
    for (int it = 0; it < 16; ++it) {
        int mm = mb + it * 4;
        tile[mm][kk] = W[(size_t)(m0 + mm) * Kdim + k0 + kk];
    }
    __syncthreads();
    #pragma unroll
    for (int cc = 0; cc < 2; ++cc) {
        int c = t + cc * 256;
        int kp = c >> 6, m = c & 63;
        u16 hi[8], lo[8];
        #pragma unroll
        for (int j = 0; j < 8; ++j) {
            float v = tile[m][kp * 8 + j];
            u16 h = f2h(v);
            hi[j] = h;
            lo[j] = f2h(v - h2f(h));
        }
        size_t o = ((size_t)(k0 / 8 + kp) * CH + m0 + m) * 8;
        *(uint4*)&Hi[o] = *(const uint4*)hi;
        *(uint4*)&Lo[o] = *(const uint4*)lo;
    }
}

// =====================================================================================
// pack_hvT: Hv fp32 [C][N] (batched) -> HvT packed [N/8][C][8] hi/lo and (Hv^2)T hi/lo
// grid: (N/64, C/64, 2=batch)
// =====================================================================================
__global__ __launch_bounds__(256) void pack_hvT(const float* __restrict__ Hv,
    u16* __restrict__ H1h, u16* __restrict__ H1l,
    u16* __restrict__ H2h, u16* __restrict__ H2l)
{
    __shared__ float tile[64][65];
    const int t = threadIdx.x;
    const int s0 = blockIdx.x * 64, c0 = blockIdx.y * 64;
    const int z = blockIdx.z;
    const float* src = Hv + (size_t)z * CH * NS;
    const int ss = t & 63, cb = t >> 6;
    #pragma unroll
    for (int it = 0; it < 16; ++it) {
        int cc = cb + it * 4;
        tile[cc][ss] = src[(size_t)(c0 + cc) * NS + s0 + ss];
    }
    __syncthreads();
    const size_t zb = (size_t)z * NS * CH;
    #pragma unroll
    for (int cc2 = 0; cc2 < 2; ++cc2) {
        int c = t + cc2 * 256;
        int sp = c >> 6, cm = c & 63;
        u16 h1[8], l1[8], h2[8], l2[8];
        #pragma unroll
        for (int j = 0; j < 8; ++j) {
            float v = tile[cm][sp * 8 + j];
            u16 a = f2h(v); h1[j] = a; l1[j] = f2h(v - h2f(a));
            float v2 = v * v;
            u16 b = f2h(v2); h2[j] = b; l2[j] = f2h(v2 - h2f(b));
        }
        size_t o = zb + ((size_t)(s0 / 8 + sp) * CH + c0 + cm) * 8;
        *(uint4*)&H1h[o] = *(const uint4*)h1;
        *(uint4*)&H1l[o] = *(const uint4*)l1;
        *(uint4*)&H2h[o] = *(const uint4*)h2;
        *(uint4*)&H2l[o] = *(const uint4*)l2;
    }
}

// =====================================================================================
// colstats_comb64: combine 64 row-group partials -> column max + 1/sum
// =====================================================================================
__global__ __launch_bounds__(256) void colstats_comb64(const float* __restrict__ pm,
    const float* __restrict__ ps, float* __restrict__ mx, float* __restrict__ inv)
{
    const int n = blockIdx.x * 256 + threadIdx.x;
    float m = -3.0e38f, s = 0.f;
    #pragma unroll 8
    for (int g = 0; g < 64; ++g) {
        float gm = pm[(size_t)g * NS + n], gs = ps[(size_t)g * NS + n];
        float nm = fmaxf(m, gm);
        s = s * __expf(m - nm) + gs * __expf(gm - nm);
        m = nm;
    }
    mx[n] = m;
    inv[n] = 1.f / s;
}

// ================= per-(b,c) content stats =================
__global__ __launch_bounds__(256) void content_stats(const float* __restrict__ content,
                                                     float* __restrict__ cmean,
                                                     float* __restrict__ cinv)
{
    const int bc = blockIdx.x;
    const float4* p = (const float4*)(content + (size_t)bc * NS);
    const int t = threadIdx.x;
    float s = 0.f, s2 = 0.f;
    #pragma unroll
    for (int j = 0; j < 4; ++j) {
        float4 v = p[t + j * 256];
        s  += (v.x + v.y) + (v.z + v.w);
        s2 += (v.x * v.x + v.y * v.y) + (v.z * v.z + v.w * v.w);
    }
    #pragma unroll
    for (int off = 32; off >= 1; off >>= 1) {
        s  += __shfl_xor(s, off);
        s2 += __shfl_xor(s2, off);
    }
    __shared__ float r1[4], r2[4];
    const int wid = t >> 6;
    if ((t & 63) == 0) { r1[wid] = s; r2[wid] = s2; }
    __syncthreads();
    if (t == 0) {
        s  = (r1[0] + r1[1]) + (r1[2] + r1[3]);
        s2 = (r2[0] + r2[1]) + (r2[2] + r2[3]);
        const float mean = s * (1.0f / 4096.f);
        const float var = (s2 - 4096.f * mean * mean) * (1.0f / 4095.f);
        cmean[bc] = mean;
        cinv[bc] = rsqrtf(fmaxf(var, 0.f) + EPSV);
    }
}

// =====================================================================================
// compute_O + fused O-pack: O = sqrt(max(Sec-Mean^2,0))*norm(content)+Mean, written
// directly as packed fp16 hi/lo [C/8][NS][8] per batch (B-operand for out conv).
// grid: (NS/256, CH/8, 2)
// =====================================================================================
__global__ __launch_bounds__(256) void compute_O_pack(
    const float* __restrict__ Mean, const float* __restrict__ Sec,
    const float* __restrict__ content,
    const float* __restrict__ cmean, const float* __restrict__ cinv,
    u16* __restrict__ Oh, u16* __restrict__ Ol)
{
    const int n  = blockIdx.x * 256 + threadIdx.x;
    const int cg = blockIdx.y;
    const int b  = blockIdx.z;
    const size_t KN = (size_t)CH * NS;
    u16 h[8], l[8];
    #pragma unroll
    for (int j = 0; j < 8; ++j) {
        const int c = cg * 8 + j;
        const size_t po = (size_t)b * KN + (size_t)c * NS + n;
        const float mn = Mean[po];
        const float sc = Sec[po];
        const float ct = content[po];
        const int bc = b * CH + c;
        const float o = sqrtf(fmaxf(sc - mn * mn, 0.f)) * ((ct - cmean[bc]) * cinv[bc]) + mn;
        h[j] = f2h(o);
        l[j] = f2h(o - h2f(h[j]));
    }
    const size_t off = (size_t)b * KN + ((size_t)cg * NS + n) * 8;
    *(uint4*)&Oh[off] = *(const uint4*)h;
    *(uint4*)&Ol[off] = *(const uint4*)l;
}

// =====================================================================================
extern "C" void kernel_launch(void* const* d_in, const int* in_sizes, int n_in,
                              void* d_out, int out_size, void* d_ws, size_t ws_size,
                              hipStream_t stream)
{
    const float* content = (const float*)d_in[0];
    const float* style   = (const float*)d_in[1];
    const float* f_w   = (const float*)d_in[2];
    const float* f_b   = (const float*)d_in[3];
    const float* g_w   = (const float*)d_in[4];
    const float* g_b   = (const float*)d_in[5];
    const float* h_w   = (const float*)d_in[6];
    const float* h_b   = (const float*)d_in[7];
    const float* out_w = (const float*)d_in[8];
    const float* out_b = (const float*)d_in[9];
    float* out = (float*)d_out;

    char* ws = (char*)d_ws;
    size_t off = 0;
    auto alloc = [&](size_t bytes) -> void* {
        void* p = ws + off;
        off = (off + bytes + 255) & ~(size_t)255;
        return p;
    };

    const size_t KN   = (size_t)CH * NS;      // 2,097,152 elements (one batch plane)
    const size_t CHCH = (size_t)CH * CH;
    const long   NSNS = (long)NS * NS;

    // ---- weight packs ----
    u16 *Wh[4], *Wl[4];
    for (int w = 0; w < 4; ++w) { Wh[w] = (u16*)alloc(CHCH * 2); Wl[w] = (u16*)alloc(CHCH * 2); }

    // ---- R2: one 8*KN u16 region, two time-disjoint layouts:
    //   phase 1 (conv inputs):  [Xc_hi | Xc_lo | Xs_hi | Xs_lo]          (each 2KN)
    //   phase 2 (PV A-packs):   [HvT_hi | Hv2T_hi | HvT_lo | Hv2T_lo]    (each 2KN)
    u16* R2 = (u16*)alloc(8 * KN * 2);
    u16* Xc_hi = R2;            u16* Xc_lo = R2 + 2 * KN;
    u16* Xs_hi = R2 + 4 * KN;   u16* Xs_lo = R2 + 6 * KN;
    u16* HvT_hi  = R2;
    u16* Hv2T_hi = R2 + 2 * KN;
    u16* HvT_lo  = R2 + 4 * KN;
    u16* Hv2T_lo = R2 + 6 * KN;

    // ---- R3: [Fqp_hi | Fqp_lo | Gkp_hi | Gkp_lo], each 2KN u16; Gk reused as O pack ----
    u16* Fqp_hi = (u16*)alloc(2 * KN * 2);  u16* Fqp_lo = (u16*)alloc(2 * KN * 2);
    u16* Gkp_hi = (u16*)alloc(2 * KN * 2);  u16* Gkp_lo = (u16*)alloc(2 * KN * 2);
    u16* Op_hi = Gkp_hi;  u16* Op_lo = Gkp_lo;

    // ---- R4: P packs (hi only), BOTH batches for merged PV ----
    u16* Pp = (u16*)alloc(2 * (size_t)NS * NS * 2);

    // ---- R5: fp32 union: Hv32 -> S32 (67.2 MB) ----
    char* R5 = (char*)alloc((size_t)NS * NS * 4);
    float* Hv32 = (float*)(R5 + 4 * KN * 4);   // conv z=4,5 output (dead after pack_hvT)
    float* S32  = (float*)R5;

    // ---- R6: Mean/Sec fp32, contiguous (Sec32 = Mean32 + 2KN floats) ----
    float* Mean32 = (float*)alloc(2 * KN * 4);
    float* Sec32  = (float*)alloc(2 * KN * 4);

    // ---- small ----
    float* pm    = (float*)alloc(64 * NS * 4);
    float* ps    = (float*)alloc(64 * NS * 4);
    float* mxv   = (float*)alloc(NS * 4);
    float* invv  = (float*)alloc(NS * 4);
    float* cmean = (float*)alloc(1024 * 4);
    float* cinv  = (float*)alloc(1024 * 4);
    (void)ws_size; (void)in_sizes; (void)n_in; (void)out_size;

    // ================= pipeline =================
    packA_T<<<dim3(8, 8), 256, 0, stream>>>(f_w,   Wh[0], Wl[0], CH);
    packA_T<<<dim3(8, 8), 256, 0, stream>>>(g_w,   Wh[1], Wl[1], CH);
    packA_T<<<dim3(8, 8), 256, 0, stream>>>(h_w,   Wh[2], Wl[2], CH);
    packA_T<<<dim3(8, 8), 256, 0, stream>>>(out_w, Wh[3], Wl[3], CH);
    packB_k<false, true><<<dim3(16, 64, 2), 256, 0, stream>>>(content, Xc_hi, Xc_lo, nullptr, nullptr, NS, (long)KN, (long)KN);
    packB_k<false, true><<<dim3(16, 64, 2), 256, 0, stream>>>(style,   Xs_hi, Xs_lo, nullptr, nullptr, NS, (long)KN, (long)KN);
    content_stats<<<1024, 256, 0, stream>>>(content, cmean, cinv);

    // ---- merged conv3: z = w*2 + b; w=0 (f,content)->Fqp packed, w=1 (g,style)->Gkp
    //      packed, w=2 (h,style)->Hv32 fp32 ----
    {
        ZTab tb = {};
        const float* bs[3] = { f_b, g_b, h_b };
        for (int z = 0; z < 6; ++z) {
            const int w = z >> 1, b = z & 1;
            tb.aoff[z] = (long)(2 * w) * CHCH;
            tb.boff[z] = (w == 0 ? 0 : (long)(4 * KN)) + (long)b * KN;
            tb.mode[z] = (w < 2) ? 1 : 0;
            tb.ooff[z] = (w < 2) ? ((long)w * 4 * KN + (long)b * KN)   // u16 elems from Fqp base
                                 : ((long)4 * KN + (long)b * KN);      // fp32 elems from R5 base
            tb.bias[z] = bs[w];
        }
        gemm_split<4, false, false><<<dim3(32, 4, 6), 256, 0, stream>>>(
            Wh[0], Wh[0] + CHCH, Xc_hi, Xc_hi + 2 * KN, nullptr,
            (float*)R5, Fqp_hi, Fqp_hi + 2 * KN, nullptr, nullptr, CH, NS, CH, tb);
    }

    // transposed Hv / Hv^2 packs (overwrites R2 phase-1; Xc/Xs dead)
    pack_hvT<<<dim3(64, 8, 2), 256, 0, stream>>>(Hv32, HvT_hi, HvT_lo, Hv2T_hi, Hv2T_lo);

    for (int b = 0; b < 2; ++b) {
        const long bo = (long)b * KN;
        // QK^T (2-term): S^T[s][n] = sum_k Gk[k][s] * Fq_hi[k][n]; fused col-stats
        ZTab tq = {};
        gemm_split<3, false, true><<<dim3(32, 32, 1), 256, 0, stream>>>(
            Gkp_hi + bo, Gkp_lo + bo, Fqp_hi + bo, nullptr, nullptr,
            S32, nullptr, nullptr, pm, ps, NS, NS, CH, tq);
        colstats_comb64<<<16, 256, 0, stream>>>(pm, ps, mxv, invv);
        packB_k<true, false><<<dim3(16, 512, 1), 256, 0, stream>>>(
            S32, Pp + (size_t)b * NSNS, nullptr, mxv, invv, NS, 0, 0);
    }

    // ---- merged PV: z = b*2 + which; which=0 -> Mean (A=HvT), 1 -> Sec (A=Hv2T) ----
    {
        ZTab tp = {};
        for (int z = 0; z < 4; ++z) {
            const int b = z >> 1, which = z & 1;
            tp.aoff[z] = (long)which * 2 * KN + (long)b * KN;
            tp.boff[z] = (long)b * NSNS;
            tp.ooff[z] = (long)which * 2 * KN + (long)b * KN;
        }
        gemm_split<3, false, false><<<dim3(32, 4, 4), 256, 0, stream>>>(
            HvT_hi, HvT_lo, Pp, nullptr, nullptr,
            Mean32, nullptr, nullptr, nullptr, nullptr, CH, NS, NS, tp);
    }

    // O + fused pack (direct fp16 hi/lo packed)
    compute_O_pack<<<dim3(16, 64, 2), 256, 0, stream>>>(
        Mean32, Sec32, content, cmean, cinv, Op_hi, Op_lo);

    // ---- out conv: bias + residual(content) -> d_out ----
    {
        ZTab tf = {};
        for (int z = 0; z < 2; ++z) {
            tf.ooff[z] = (long)z * KN;
            tf.boff[z] = (long)z * KN;
            tf.bias[z] = out_b;
        }
        gemm_split<4, true, false><<<dim3(32, 4, 2), 256, 0, stream>>>(
            Wh[3], Wl[3], Op_hi, Op_lo, content,
            out, nullptr, nullptr, nullptr, nullptr, CH, NS, CH, tf);
    }
}